// Round 5
// baseline (1204.008 us; speedup 1.0000x reference)
//
#include <hip/hip_runtime.h>
#include <hip/hip_bf16.h>

#define NNODES 12000
#define NEDGES 384000
#define NETOT  (NEDGES + NNODES)   /* 396000 incl self-loops */
#define FIN    4
#define FHID   50
#define FOUT   1433
#define KP     1440                /* FOUT padded to multiple of 32 */
#define MP     12032               /* NNODES padded to multiple of 128 */
#define NTILE  (MP / 128)          /* 94 */
#define NTRI   (NTILE * (NTILE + 1) / 2)   /* 4465 upper-triangle tiles */
#define NEG_SLOPE 0.2f

typedef __hip_bfloat16 bf16_t;
typedef long long i64_t;
typedef float f32x4 __attribute__((ext_vector_type(4)));
typedef float f32x2 __attribute__((ext_vector_type(2)));

__device__ __forceinline__ float  b2f(bf16_t h) { return __bfloat162float(h); }
__device__ __forceinline__ bf16_t f2b(float f)  { return __float2bfloat16(f); }
__device__ __forceinline__ unsigned short f2bu(float f) { bf16_t h = f2b(f); return *(unsigned short*)&h; }

// ---------------- init: deg=1 (self loop), zero pad rows of h2 (fp8) ----------------
__global__ void k_init(int* __restrict__ deg, unsigned char* __restrict__ h2) {
    int i = blockIdx.x * blockDim.x + threadIdx.x;
    int stride = gridDim.x * blockDim.x;
    for (int v = i; v < NNODES; v += stride) deg[v] = 1;
    const size_t padN = (size_t)(MP - NNODES) * KP;
    for (size_t t = i; t < padN; t += stride) h2[(size_t)NNODES * KP + t] = 0;
}

// ---------------- count real edges by dst ----------------
__global__ void k_count(const int* __restrict__ ei, int* __restrict__ deg) {
    int i = blockIdx.x * blockDim.x + threadIdx.x;
    if (i < NEDGES) atomicAdd(&deg[ei[NEDGES + i]], 1);
}

// ---------------- single-block shfl exclusive scan -> rowptr[N+1] + cursor[N] ----------------
__global__ __launch_bounds__(1024) void k_scan(const int* __restrict__ deg,
                                               int* __restrict__ rowptr,
                                               int* __restrict__ cursor) {
    __shared__ int wsum[16];
    const int tid = threadIdx.x, lane = tid & 63, wv = tid >> 6;
    const int base = tid * 12;
    int pref[12];
    int s = 0;
#pragma unroll
    for (int u = 0; u < 12; ++u) {
        int idx = base + u;
        int d = (idx < NNODES) ? deg[idx] : 0;
        pref[u] = s;
        s += d;
    }
    int sc = s;   // inclusive wave scan of per-thread sums
#pragma unroll
    for (int o = 1; o < 64; o <<= 1) {
        int t2 = __shfl_up(sc, o, 64);
        if (lane >= o) sc += t2;
    }
    if (lane == 63) wsum[wv] = sc;
    __syncthreads();
    if (wv == 0 && lane < 16) {
        int mine = wsum[lane];
        int scw = mine;
#pragma unroll
        for (int o = 1; o < 16; o <<= 1) {
            int t3 = __shfl_up(scw, o, 64);
            if (lane >= o) scw += t3;
        }
        wsum[lane] = scw - mine;   // exclusive wave prefix
    }
    __syncthreads();
    const int pre = wsum[wv] + (sc - s);   // exclusive prefix of this thread
#pragma unroll
    for (int u = 0; u < 12; ++u) {
        int idx = base + u;
        if (idx < NNODES) {
            int p = pre + pref[u];
            rowptr[idx] = p;
            cursor[idx] = p;
        }
    }
    if (tid == 1023) rowptr[NNODES] = pre + s;   // == NETOT
}

// ---------------- fill CSR src lists (incl self loops) + edge passthrough ----------------
__global__ void k_fill(const int* __restrict__ ei, int* __restrict__ cursor,
                       int* __restrict__ csrc, float* __restrict__ outbase) {
    int i = blockIdx.x * blockDim.x + threadIdx.x;
    if (i < NETOT) {
        int s, d;
        if (i < NEDGES) { s = ei[i]; d = ei[NEDGES + i]; }
        else            { s = d = i - NEDGES; }
        int pos = atomicAdd(&cursor[d], 1);
        csrc[pos] = s;
    }
    if (i < 2 * NEDGES)
        outbase[(size_t)NNODES * (size_t)NNODES + (size_t)i] = (float)ei[i];
}

// ---------------- layer1 linear: h1pre = x @ W1, al1/ar1 logit parts ----------------
__global__ __launch_bounds__(256) void k_linear1(
        const bf16_t* __restrict__ x, const bf16_t* __restrict__ W1,
        const bf16_t* __restrict__ as1, const bf16_t* __restrict__ ad1,
        float* __restrict__ h1pre, float* __restrict__ al, float* __restrict__ ar) {
    __shared__ float sW[FIN * FHID];
    __shared__ float sa[FHID], sdl[FHID];
    int tid = threadIdx.x;
    if (tid < FIN * FHID) sW[tid] = b2f(W1[tid]);
    if (tid < FHID) { sa[tid] = b2f(as1[tid]); sdl[tid] = b2f(ad1[tid]); }
    __syncthreads();
    int i = blockIdx.x * 256 + tid;
    if (i >= NNODES) return;
    float x0 = b2f(x[i * 4 + 0]), x1 = b2f(x[i * 4 + 1]);
    float x2 = b2f(x[i * 4 + 2]), x3 = b2f(x[i * 4 + 3]);
    float hal = 0.f, har = 0.f;
    for (int j = 0; j < FHID; ++j) {
        float h = x0 * sW[j] + x1 * sW[FHID + j] + x2 * sW[2 * FHID + j] + x3 * sW[3 * FHID + j];
        h1pre[(size_t)i * FHID + j] = h;
        hal += h * sa[j];
        har += h * sdl[j];
    }
    al[i] = hal; ar[i] = har;
}

// ---------------- layer1 softmax-aggregate: wave-per-node, no max pass, shfl broadcast ----------------
__global__ __launch_bounds__(256) void k_agg1(
        const float* __restrict__ h1pre, const float* __restrict__ al, const float* __restrict__ ar,
        const int* __restrict__ rowptr, const int* __restrict__ csrc,
        const bf16_t* __restrict__ b1, float* __restrict__ h1) {
    const int wv = threadIdx.x >> 6, lane = threadIdx.x & 63;
    const int v = blockIdx.x * 4 + wv;        // NNODES % 4 == 0
    const int s0 = rowptr[v], s1 = rowptr[v + 1];
    const float arv = ar[v];
    float acc = 0.f, ssum = 0.f;
    for (int base = s0; base < s1; base += 64) {
        int e = base + lane;
        float w = 0.f; int si = 0;
        if (e < s1) {
            si = csrc[e];
            float l = al[si] + arv;
            l = l > 0.f ? l : NEG_SLOPE * l;
            w = __expf(l);                     // softmax is shift-invariant; |l| small
        }
        ssum += w;
        int cnt = min(64, s1 - base);
#pragma unroll 4
        for (int j = 0; j < cnt; ++j) {
            float wj = __shfl(w, j, 64);
            int   sj = __shfl(si, j, 64);
            if (lane < FHID) acc += wj * h1pre[(size_t)sj * FHID + lane];
        }
    }
#pragma unroll
    for (int o = 32; o; o >>= 1) ssum += __shfl_xor(ssum, o, 64);
    if (lane < FHID) {
        float o2 = acc / ssum + b2f(b1[lane]);
        h1[(size_t)v * FHID + lane] = fmaxf(o2, 0.f);
    }
}

// ---------------- layer2 linear: 4 nodes/block, h2pre (fp8 e4m3) = h1 @ W2, al2/ar2 ----------------
__global__ __launch_bounds__(256) void k_linear2(
        const float* __restrict__ h1, const bf16_t* __restrict__ W2,
        const bf16_t* __restrict__ as2, const bf16_t* __restrict__ ad2,
        unsigned char* __restrict__ h2pre, float* __restrict__ al2, float* __restrict__ ar2) {
    int v0 = blockIdx.x * 4, tid = threadIdx.x;
    __shared__ float sh[4][FHID];
    if (tid < 4 * FHID) sh[tid / FHID][tid % FHID] = h1[(size_t)v0 * FHID + tid];
    __syncthreads();
    float pal[4] = {0.f, 0.f, 0.f, 0.f}, par[4] = {0.f, 0.f, 0.f, 0.f};
#pragma unroll
    for (int i = 0; i < 3; ++i) {
        int f0 = i * 512 + 2 * tid;          // even feature index
        if (f0 < KP) {
            float d0[4] = {0.f, 0.f, 0.f, 0.f}, d1[4] = {0.f, 0.f, 0.f, 0.f};
            bool ok0 = f0 < FOUT, ok1 = f0 + 1 < FOUT;
            if (ok0) {
                int f1 = ok1 ? f0 + 1 : f0;  // safe aliased read when f0+1 OOB
#pragma unroll 10
                for (int k = 0; k < FHID; ++k) {
                    float w0 = b2f(W2[k * FOUT + f0]);
                    float w1 = b2f(W2[k * FOUT + f1]);
#pragma unroll
                    for (int c = 0; c < 4; ++c) {
                        d0[c] += sh[c][k] * w0;
                        d1[c] += sh[c][k] * w1;
                    }
                }
                if (!ok1) { d1[0] = d1[1] = d1[2] = d1[3] = 0.f; }
                float sa0 = b2f(as2[f0]), sd0 = b2f(ad2[f0]);
                float sa1 = ok1 ? b2f(as2[f0 + 1]) : 0.f;
                float sd1 = ok1 ? b2f(ad2[f0 + 1]) : 0.f;
#pragma unroll
                for (int c = 0; c < 4; ++c) {
                    pal[c] += d0[c] * sa0 + d1[c] * sa1;
                    par[c] += d0[c] * sd0 + d1[c] * sd1;
                }
            }
#pragma unroll
            for (int c = 0; c < 4; ++c) {
                int pk = __builtin_amdgcn_cvt_pk_fp8_f32(d0[c], d1[c], 0, false);
                *(unsigned short*)(h2pre + (size_t)(v0 + c) * KP + f0) = (unsigned short)pk;
            }
        }
    }
#pragma unroll
    for (int off = 32; off; off >>= 1)
#pragma unroll
        for (int c = 0; c < 4; ++c) {
            pal[c] += __shfl_xor(pal[c], off, 64);
            par[c] += __shfl_xor(par[c], off, 64);
        }
    __shared__ float rA[4][4], rB[4][4];
    int wave = tid >> 6, lane = tid & 63;
    if (lane == 0)
#pragma unroll
        for (int c = 0; c < 4; ++c) { rA[wave][c] = pal[c]; rB[wave][c] = par[c]; }
    __syncthreads();
    if (tid < 4) {
        al2[v0 + tid] = rA[0][tid] + rA[1][tid] + rA[2][tid] + rA[3][tid];
        ar2[v0 + tid] = rB[0][tid] + rB[1][tid] + rB[2][tid] + rB[3][tid];
    }
}

// ---------------- layer2 softmax-aggregate: fp8 gather, no max pass, fp8 h2 out ----------------
__global__ __launch_bounds__(256) void k_agg2(
        const unsigned char* __restrict__ h2pre, const float* __restrict__ al, const float* __restrict__ ar,
        const int* __restrict__ rowptr, const int* __restrict__ csrc,
        const bf16_t* __restrict__ bias2, unsigned char* __restrict__ h2) {
    int v = blockIdx.x, tid = threadIdx.x;
    int s0 = rowptr[v], s1 = rowptr[v + 1];
    float arv = ar[v];
    int wave = tid >> 6, lane = tid & 63;

    float acc[8] = {0.f, 0.f, 0.f, 0.f, 0.f, 0.f, 0.f, 0.f};
    float ssum = 0.f;
    __shared__ float sw[256];
    __shared__ int ssrc[256];
    __shared__ float red[4];
    const bool act = tid < (KP / 8);          // 180 lanes cover the 1440-B row
    for (int base = s0; base < s1; base += 256) {
        int e = base + tid;
        float w = 0.f; int si = 0;
        if (e < s1) {
            si = csrc[e];
            float l = al[si] + arv;
            l = l > 0.f ? l : NEG_SLOPE * l;
            w = __expf(l);                    // shift-invariant; |l| small
        }
        ssum += w;
        sw[tid] = w; ssrc[tid] = si;
        __syncthreads();
        int cnt = min(256, s1 - base);
        if (act) {
#pragma unroll 8
            for (int j = 0; j < cnt; ++j) {
                float wj = sw[j];
                const uint2* hp = (const uint2*)(h2pre + (size_t)ssrc[j] * KP);
                uint2 p = hp[tid];
                f32x2 e0 = __builtin_amdgcn_cvt_pk_f32_fp8(p.x, false);
                f32x2 e1 = __builtin_amdgcn_cvt_pk_f32_fp8(p.x, true);
                f32x2 e2 = __builtin_amdgcn_cvt_pk_f32_fp8(p.y, false);
                f32x2 e3 = __builtin_amdgcn_cvt_pk_f32_fp8(p.y, true);
                acc[0] += wj * e0.x; acc[1] += wj * e0.y;
                acc[2] += wj * e1.x; acc[3] += wj * e1.y;
                acc[4] += wj * e2.x; acc[5] += wj * e2.y;
                acc[6] += wj * e3.x; acc[7] += wj * e3.y;
            }
        }
        __syncthreads();
    }
#pragma unroll
    for (int off = 32; off; off >>= 1) ssum += __shfl_xor(ssum, off, 64);
    if (lane == 0) red[wave] = ssum;
    __syncthreads();
    float inv = 1.f / (red[0] + red[1] + red[2] + red[3]);

    if (act) {
        int fb = 8 * tid;
        float o[8];
#pragma unroll
        for (int t = 0; t < 8; ++t) {
            int f = fb + t;
            o[t] = (f < FOUT) ? fmaxf(acc[t] * inv + b2f(bias2[f]), 0.f) : 0.f;
        }
        // pack 8 f32 -> 8 fp8 e4m3
        unsigned w0 = (unsigned)__builtin_amdgcn_cvt_pk_fp8_f32(o[0], o[1], 0, false) & 0xffffu;
        w0 |= ((unsigned)__builtin_amdgcn_cvt_pk_fp8_f32(o[2], o[3], 0, false) & 0xffffu) << 16;
        unsigned w1 = (unsigned)__builtin_amdgcn_cvt_pk_fp8_f32(o[4], o[5], 0, false) & 0xffffu;
        w1 |= ((unsigned)__builtin_amdgcn_cvt_pk_fp8_f32(o[6], o[7], 0, false) & 0xffffu) << 16;
        uint2 pk; pk.x = w0; pk.y = w1;
        *(uint2*)(h2 + (size_t)v * KP + fb) = pk;
    }
}

// ---------------- final: out = sigmoid(H @ H^T), FP8 MFMA, 1-D triangular grid ----------------
// Round-5 change: H is stored FP8 e4m3 (17.3 MB vs 34.65 MB bf16). The GEMM was
// shown (R1-R4: four schedules, identical 380 us, identical MfmaUtil 22%) to be
// bound by combined L3+HBM traffic at ~5.9 TB/s, not by schedule/LDS/MFMA.
// FP8 halves the entire read stream (HBM, L3, DMA, LDS). Same m97 128x128
// structure: 4 waves, BK=32, gload_lds DMA staging (1 instr/matrix/wave/step,
// linear LDS: lane*16 == rowmajor 32-B fp8 rows), mfma_f32_16x16x32_fp8_fp8
// (same K-indexing and C/D layout as the bf16 variant). Frag reads are
// ds_read_b64 at row*32+q*8 (4-way bank alias, non-critical pipe). 45 K-steps
// exactly (1440/32), no tail. nt stores + bijective XCD tile swizzle kept.
__global__ __launch_bounds__(256) void k_gemm_sig(const unsigned char* __restrict__ Hm,
                                                  float* __restrict__ out) {
    // XCD-bijective swizzle of the linear tile id (grid round-robins XCDs)
    int orig = blockIdx.x;
    int xcd = orig & 7, ii = orig >> 3;
    int t = (xcd == 0) ? ii : (559 + (xcd - 1) * 558 + ii);   // q=558, r=1
    // decode linear tile id -> (by, bx) with bx >= by
    int by = (int)((2 * NTILE + 1 - sqrtf((float)(2 * NTILE + 1) * (2 * NTILE + 1) - 8.0f * t)) * 0.5f);
    if (by < 0) by = 0;
    if (by > NTILE - 1) by = NTILE - 1;
    while (by + 1 < NTILE && (by + 1) * NTILE - ((by + 1) * by) / 2 <= t) ++by;
    while (by > 0 && by * NTILE - (by * (by - 1)) / 2 > t) --by;
    int bx = by + (t - (by * NTILE - (by * (by - 1)) / 2));

    __shared__ __align__(16) unsigned char As[128 * 32];   // 4 KB fp8
    __shared__ __align__(16) unsigned char Bs[128 * 32];   // 4 KB fp8
    const int tid = threadIdx.x;
    const int wave = tid >> 6;
    const int lane = tid & 63;
    const int rowA0 = by * 128;
    const int rowB0 = bx * 128;

    // staging: per wave ONE gload_lds per matrix per K-step.
    // LDS dest linear (wave*1024 + lane*16) == row-major [128][32] fp8 with
    // row = wave*32 + (lane>>1), k-half = lane&1  (lane*16 = (lane>>1)*32 + (lane&1)*16).
    const int sRow = wave * 32 + (lane >> 1);
    const int sOff = (lane & 1) * 16;
    const unsigned char* gA = Hm + (size_t)(rowA0 + sRow) * KP + sOff;
    const unsigned char* gB = Hm + (size_t)(rowB0 + sRow) * KP + sOff;

    f32x4 acc[4][4] = {};

    const int wrow = wave >> 1, wcol = wave & 1;
    const int r = lane & 15, q = lane >> 4;

    for (int kt = 0; kt < KP / 32; ++kt) {
        const int k0 = kt * 32;
        __builtin_amdgcn_global_load_lds(
            (const __attribute__((address_space(1))) void*)(gA + k0),
            (__attribute__((address_space(3))) void*)((char*)As + wave * 1024 + lane * 16),
            16, 0, 0);
        __builtin_amdgcn_global_load_lds(
            (const __attribute__((address_space(1))) void*)(gB + k0),
            (__attribute__((address_space(3))) void*)((char*)Bs + wave * 1024 + lane * 16),
            16, 0, 0);
        __syncthreads();
        i64_t af[4], bfr[4];
#pragma unroll
        for (int mi = 0; mi < 4; ++mi)
            af[mi] = *(const i64_t*)(As + (wrow * 64 + mi * 16 + r) * 32 + q * 8);
#pragma unroll
        for (int ni = 0; ni < 4; ++ni)
            bfr[ni] = *(const i64_t*)(Bs + (wcol * 64 + ni * 16 + r) * 32 + q * 8);
#pragma unroll
        for (int mi = 0; mi < 4; ++mi)
#pragma unroll
            for (int ni = 0; ni < 4; ++ni)
                acc[mi][ni] = __builtin_amdgcn_mfma_f32_16x16x32_fp8_fp8(af[mi], bfr[ni], acc[mi][ni], 0, 0, 0);
        __syncthreads();
    }

    // epilogue. C/D layout: col=lane&15, row=(lane>>4)*4+reg. N%4==0, row0%4==0.
    // Output stores NON-TEMPORAL: pure streaming, never re-read.
#pragma unroll
    for (int mi = 0; mi < 4; ++mi) {
        const int row0 = rowA0 + wrow * 64 + mi * 16 + q * 4;
#pragma unroll
        for (int ni = 0; ni < 4; ++ni) {
            const int col = rowB0 + wcol * 64 + ni * 16 + r;
            if (col < NNODES && row0 < NNODES) {
                f32x4 s;
#pragma unroll
                for (int r2 = 0; r2 < 4; ++r2)
                    s[r2] = 1.f / (1.f + __expf(-acc[mi][ni][r2]));
#pragma unroll
                for (int r2 = 0; r2 < 4; ++r2)
                    __builtin_nontemporal_store(s[r2], out + (size_t)(row0 + r2) * NNODES + col);
                if (bx != by)   // mirrored tile: contiguous float4 store
                    __builtin_nontemporal_store(s, (f32x4*)(out + (size_t)col * NNODES + row0));
            }
        }
    }
}

extern "C" void kernel_launch(void* const* d_in, const int* in_sizes, int n_in,
                              void* d_out, int out_size, void* d_ws, size_t ws_size,
                              hipStream_t stream) {
    const bf16_t* x   = (const bf16_t*)d_in[0];
    const int*    ei  = (const int*)d_in[1];
    const bf16_t* W1  = (const bf16_t*)d_in[2];
    const bf16_t* as1 = (const bf16_t*)d_in[3];
    const bf16_t* ad1 = (const bf16_t*)d_in[4];
    const bf16_t* b1  = (const bf16_t*)d_in[5];
    const bf16_t* W2  = (const bf16_t*)d_in[6];
    const bf16_t* as2 = (const bf16_t*)d_in[7];
    const bf16_t* ad2 = (const bf16_t*)d_in[8];
    const bf16_t* b2  = (const bf16_t*)d_in[9];
    float* out = (float*)d_out;   // output 0 f32 [N][N], output 1 f32 [2][E]

    // Scratch lives inside d_out's adjacency region (576 MB f32), dead until
    // k_gemm_sig overwrites it. Only h2 (read during final GEMM) is in d_ws.
    char* obuf = (char*)d_out;
    size_t off = 0;
    auto carve = [&](size_t bytes) {
        char* p = obuf + off;
        off += (bytes + 255) & ~(size_t)255;
        return p;
    };
    float* h1pre  = (float*)carve((size_t)NNODES * FHID * 4);
    float* al1    = (float*)carve((size_t)NNODES * 4);
    float* ar1    = (float*)carve((size_t)NNODES * 4);
    float* h1     = (float*)carve((size_t)NNODES * FHID * 4);
    float* al2    = (float*)carve((size_t)NNODES * 4);
    float* ar2    = (float*)carve((size_t)NNODES * 4);
    int*   deg    = (int*)carve((size_t)NNODES * 4);
    int*   rowptr = (int*)carve((size_t)(NNODES + 1) * 4);
    int*   cursor = (int*)carve((size_t)NNODES * 4);
    int*   csrc   = (int*)carve((size_t)NETOT * 4);
    unsigned char* h2pre = (unsigned char*)carve((size_t)NNODES * KP);  // fp8
    unsigned char* h2 = (unsigned char*)d_ws;   // [MP][KP] fp8 = 17.3 MB
    (void)ws_size; (void)in_sizes; (void)n_in; (void)out_size;

    hipLaunchKernelGGL(k_init,    dim3(256), dim3(256), 0, stream, deg, h2);
    hipLaunchKernelGGL(k_count,   dim3((NEDGES + 255) / 256), dim3(256), 0, stream, ei, deg);
    hipLaunchKernelGGL(k_scan,    dim3(1), dim3(1024), 0, stream, deg, rowptr, cursor);
    hipLaunchKernelGGL(k_fill,    dim3((2 * NEDGES + 255) / 256), dim3(256), 0, stream,
                       ei, cursor, csrc, out);
    hipLaunchKernelGGL(k_linear1, dim3((NNODES + 255) / 256), dim3(256), 0, stream,
                       x, W1, as1, ad1, h1pre, al1, ar1);
    hipLaunchKernelGGL(k_agg1,    dim3(NNODES / 4), dim3(256), 0, stream,
                       h1pre, al1, ar1, rowptr, csrc, b1, h1);
    hipLaunchKernelGGL(k_linear2, dim3(NNODES / 4), dim3(256), 0, stream,
                       h1, W2, as2, ad2, h2pre, al2, ar2);
    hipLaunchKernelGGL(k_agg2,    dim3(NNODES), dim3(256), 0, stream,
                       h2pre, al2, ar2, rowptr, csrc, b2, h2);
    hipLaunchKernelGGL(k_gemm_sig, dim3(NTRI), dim3(256), 0, stream, h2, out);
}

// Round 6
// 1177.757 us; speedup vs baseline: 1.0223x; 1.0223x over previous
//
#include <hip/hip_runtime.h>
#include <hip/hip_bf16.h>

#define NNODES 12000
#define NEDGES 384000
#define NETOT  (NEDGES + NNODES)   /* 396000 incl self-loops */
#define FIN    4
#define FHID   50
#define FOUT   1433
#define KP     1440                /* FOUT padded to multiple of 32 */
#define MP     12032               /* NNODES padded to multiple of 128 */
#define NTILE  (MP / 128)          /* 94 */
#define NTRI   (NTILE * (NTILE + 1) / 2)   /* 4465 upper-triangle tiles */
#define NEG_SLOPE 0.2f

typedef __hip_bfloat16 bf16_t;
typedef __bf16 bf16x8 __attribute__((ext_vector_type(8)));
typedef float f32x4 __attribute__((ext_vector_type(4)));
typedef float f32x2 __attribute__((ext_vector_type(2)));

__device__ __forceinline__ float  b2f(bf16_t h) { return __bfloat162float(h); }
__device__ __forceinline__ bf16_t f2b(float f)  { return __float2bfloat16(f); }
__device__ __forceinline__ unsigned short f2bu(float f) { bf16_t h = f2b(f); return *(unsigned short*)&h; }

// ---------------- init: deg=1 (self loop), zero pad rows of h2 (bf16) ----------------
__global__ void k_init(int* __restrict__ deg, bf16_t* __restrict__ h2) {
    int i = blockIdx.x * blockDim.x + threadIdx.x;
    int stride = gridDim.x * blockDim.x;
    for (int v = i; v < NNODES; v += stride) deg[v] = 1;
    const size_t padN = (size_t)(MP - NNODES) * KP;
    for (size_t t = i; t < padN; t += stride) h2[(size_t)NNODES * KP + t] = f2b(0.f);
}

// ---------------- count real edges by dst ----------------
__global__ void k_count(const int* __restrict__ ei, int* __restrict__ deg) {
    int i = blockIdx.x * blockDim.x + threadIdx.x;
    if (i < NEDGES) atomicAdd(&deg[ei[NEDGES + i]], 1);
}

// ---------------- single-block shfl exclusive scan -> rowptr[N+1] + cursor[N] ----------------
__global__ __launch_bounds__(1024) void k_scan(const int* __restrict__ deg,
                                               int* __restrict__ rowptr,
                                               int* __restrict__ cursor) {
    __shared__ int wsum[16];
    const int tid = threadIdx.x, lane = tid & 63, wv = tid >> 6;
    const int base = tid * 12;
    int pref[12];
    int s = 0;
#pragma unroll
    for (int u = 0; u < 12; ++u) {
        int idx = base + u;
        int d = (idx < NNODES) ? deg[idx] : 0;
        pref[u] = s;
        s += d;
    }
    int sc = s;   // inclusive wave scan of per-thread sums
#pragma unroll
    for (int o = 1; o < 64; o <<= 1) {
        int t2 = __shfl_up(sc, o, 64);
        if (lane >= o) sc += t2;
    }
    if (lane == 63) wsum[wv] = sc;
    __syncthreads();
    if (wv == 0 && lane < 16) {
        int mine = wsum[lane];
        int scw = mine;
#pragma unroll
        for (int o = 1; o < 16; o <<= 1) {
            int t3 = __shfl_up(scw, o, 64);
            if (lane >= o) scw += t3;
        }
        wsum[lane] = scw - mine;   // exclusive wave prefix
    }
    __syncthreads();
    const int pre = wsum[wv] + (sc - s);   // exclusive prefix of this thread
#pragma unroll
    for (int u = 0; u < 12; ++u) {
        int idx = base + u;
        if (idx < NNODES) {
            int p = pre + pref[u];
            rowptr[idx] = p;
            cursor[idx] = p;
        }
    }
    if (tid == 1023) rowptr[NNODES] = pre + s;   // == NETOT
}

// ---------------- fill CSR src lists (incl self loops) + edge passthrough ----------------
__global__ void k_fill(const int* __restrict__ ei, int* __restrict__ cursor,
                       int* __restrict__ csrc, float* __restrict__ outbase) {
    int i = blockIdx.x * blockDim.x + threadIdx.x;
    if (i < NETOT) {
        int s, d;
        if (i < NEDGES) { s = ei[i]; d = ei[NEDGES + i]; }
        else            { s = d = i - NEDGES; }
        int pos = atomicAdd(&cursor[d], 1);
        csrc[pos] = s;
    }
    if (i < 2 * NEDGES)
        outbase[(size_t)NNODES * (size_t)NNODES + (size_t)i] = (float)ei[i];
}

// ---------------- layer1 linear: h1pre = x @ W1, al1/ar1 logit parts ----------------
__global__ __launch_bounds__(256) void k_linear1(
        const bf16_t* __restrict__ x, const bf16_t* __restrict__ W1,
        const bf16_t* __restrict__ as1, const bf16_t* __restrict__ ad1,
        float* __restrict__ h1pre, float* __restrict__ al, float* __restrict__ ar) {
    __shared__ float sW[FIN * FHID];
    __shared__ float sa[FHID], sdl[FHID];
    int tid = threadIdx.x;
    if (tid < FIN * FHID) sW[tid] = b2f(W1[tid]);
    if (tid < FHID) { sa[tid] = b2f(as1[tid]); sdl[tid] = b2f(ad1[tid]); }
    __syncthreads();
    int i = blockIdx.x * 256 + tid;
    if (i >= NNODES) return;
    float x0 = b2f(x[i * 4 + 0]), x1 = b2f(x[i * 4 + 1]);
    float x2 = b2f(x[i * 4 + 2]), x3 = b2f(x[i * 4 + 3]);
    float hal = 0.f, har = 0.f;
    for (int j = 0; j < FHID; ++j) {
        float h = x0 * sW[j] + x1 * sW[FHID + j] + x2 * sW[2 * FHID + j] + x3 * sW[3 * FHID + j];
        h1pre[(size_t)i * FHID + j] = h;
        hal += h * sa[j];
        har += h * sdl[j];
    }
    al[i] = hal; ar[i] = har;
}

// ---------------- layer1 softmax-aggregate: wave-per-node, no max pass, shfl broadcast ----------------
__global__ __launch_bounds__(256) void k_agg1(
        const float* __restrict__ h1pre, const float* __restrict__ al, const float* __restrict__ ar,
        const int* __restrict__ rowptr, const int* __restrict__ csrc,
        const bf16_t* __restrict__ b1, float* __restrict__ h1) {
    const int wv = threadIdx.x >> 6, lane = threadIdx.x & 63;
    const int v = blockIdx.x * 4 + wv;        // NNODES % 4 == 0
    const int s0 = rowptr[v], s1 = rowptr[v + 1];
    const float arv = ar[v];
    float acc = 0.f, ssum = 0.f;
    for (int base = s0; base < s1; base += 64) {
        int e = base + lane;
        float w = 0.f; int si = 0;
        if (e < s1) {
            si = csrc[e];
            float l = al[si] + arv;
            l = l > 0.f ? l : NEG_SLOPE * l;
            w = __expf(l);                     // softmax is shift-invariant; |l| small
        }
        ssum += w;
        int cnt = min(64, s1 - base);
#pragma unroll 4
        for (int j = 0; j < cnt; ++j) {
            float wj = __shfl(w, j, 64);
            int   sj = __shfl(si, j, 64);
            if (lane < FHID) acc += wj * h1pre[(size_t)sj * FHID + lane];
        }
    }
#pragma unroll
    for (int o = 32; o; o >>= 1) ssum += __shfl_xor(ssum, o, 64);
    if (lane < FHID) {
        float o2 = acc / ssum + b2f(b1[lane]);
        h1[(size_t)v * FHID + lane] = fmaxf(o2, 0.f);
    }
}

// ---------------- layer2 linear: 4 nodes/block, h2pre (fp8 e4m3) = h1 @ W2, al2/ar2 ----------------
__global__ __launch_bounds__(256) void k_linear2(
        const float* __restrict__ h1, const bf16_t* __restrict__ W2,
        const bf16_t* __restrict__ as2, const bf16_t* __restrict__ ad2,
        unsigned char* __restrict__ h2pre, float* __restrict__ al2, float* __restrict__ ar2) {
    int v0 = blockIdx.x * 4, tid = threadIdx.x;
    __shared__ float sh[4][FHID];
    if (tid < 4 * FHID) sh[tid / FHID][tid % FHID] = h1[(size_t)v0 * FHID + tid];
    __syncthreads();
    float pal[4] = {0.f, 0.f, 0.f, 0.f}, par[4] = {0.f, 0.f, 0.f, 0.f};
#pragma unroll
    for (int i = 0; i < 3; ++i) {
        int f0 = i * 512 + 2 * tid;          // even feature index
        if (f0 < KP) {
            float d0[4] = {0.f, 0.f, 0.f, 0.f}, d1[4] = {0.f, 0.f, 0.f, 0.f};
            bool ok0 = f0 < FOUT, ok1 = f0 + 1 < FOUT;
            if (ok0) {
                int f1 = ok1 ? f0 + 1 : f0;  // safe aliased read when f0+1 OOB
#pragma unroll 10
                for (int k = 0; k < FHID; ++k) {
                    float w0 = b2f(W2[k * FOUT + f0]);
                    float w1 = b2f(W2[k * FOUT + f1]);
#pragma unroll
                    for (int c = 0; c < 4; ++c) {
                        d0[c] += sh[c][k] * w0;
                        d1[c] += sh[c][k] * w1;
                    }
                }
                if (!ok1) { d1[0] = d1[1] = d1[2] = d1[3] = 0.f; }
                float sa0 = b2f(as2[f0]), sd0 = b2f(ad2[f0]);
                float sa1 = ok1 ? b2f(as2[f0 + 1]) : 0.f;
                float sd1 = ok1 ? b2f(ad2[f0 + 1]) : 0.f;
#pragma unroll
                for (int c = 0; c < 4; ++c) {
                    pal[c] += d0[c] * sa0 + d1[c] * sa1;
                    par[c] += d0[c] * sd0 + d1[c] * sd1;
                }
            }
#pragma unroll
            for (int c = 0; c < 4; ++c) {
                int pk = __builtin_amdgcn_cvt_pk_fp8_f32(d0[c], d1[c], 0, false);
                *(unsigned short*)(h2pre + (size_t)(v0 + c) * KP + f0) = (unsigned short)pk;
            }
        }
    }
#pragma unroll
    for (int off = 32; off; off >>= 1)
#pragma unroll
        for (int c = 0; c < 4; ++c) {
            pal[c] += __shfl_xor(pal[c], off, 64);
            par[c] += __shfl_xor(par[c], off, 64);
        }
    __shared__ float rA[4][4], rB[4][4];
    int wave = tid >> 6, lane = tid & 63;
    if (lane == 0)
#pragma unroll
        for (int c = 0; c < 4; ++c) { rA[wave][c] = pal[c]; rB[wave][c] = par[c]; }
    __syncthreads();
    if (tid < 4) {
        al2[v0 + tid] = rA[0][tid] + rA[1][tid] + rA[2][tid] + rA[3][tid];
        ar2[v0 + tid] = rB[0][tid] + rB[1][tid] + rB[2][tid] + rB[3][tid];
    }
}

// ---------------- layer2 softmax-aggregate: fp8 gather, no max pass, bf16 h2 out ----------------
__global__ __launch_bounds__(256) void k_agg2(
        const unsigned char* __restrict__ h2pre, const float* __restrict__ al, const float* __restrict__ ar,
        const int* __restrict__ rowptr, const int* __restrict__ csrc,
        const bf16_t* __restrict__ bias2, bf16_t* __restrict__ h2) {
    int v = blockIdx.x, tid = threadIdx.x;
    int s0 = rowptr[v], s1 = rowptr[v + 1];
    float arv = ar[v];
    int wave = tid >> 6, lane = tid & 63;

    float acc[8] = {0.f, 0.f, 0.f, 0.f, 0.f, 0.f, 0.f, 0.f};
    float ssum = 0.f;
    __shared__ float sw[256];
    __shared__ int ssrc[256];
    __shared__ float red[4];
    const bool act = tid < (KP / 8);          // 180 lanes cover the 1440-B row
    for (int base = s0; base < s1; base += 256) {
        int e = base + tid;
        float w = 0.f; int si = 0;
        if (e < s1) {
            si = csrc[e];
            float l = al[si] + arv;
            l = l > 0.f ? l : NEG_SLOPE * l;
            w = __expf(l);                    // shift-invariant; |l| small
        }
        ssum += w;
        sw[tid] = w; ssrc[tid] = si;
        __syncthreads();
        int cnt = min(256, s1 - base);
        if (act) {
#pragma unroll 8
            for (int j = 0; j < cnt; ++j) {
                float wj = sw[j];
                const uint2* hp = (const uint2*)(h2pre + (size_t)ssrc[j] * KP);
                uint2 p = hp[tid];
                f32x2 e0 = __builtin_amdgcn_cvt_pk_f32_fp8(p.x, false);
                f32x2 e1 = __builtin_amdgcn_cvt_pk_f32_fp8(p.x, true);
                f32x2 e2 = __builtin_amdgcn_cvt_pk_f32_fp8(p.y, false);
                f32x2 e3 = __builtin_amdgcn_cvt_pk_f32_fp8(p.y, true);
                acc[0] += wj * e0.x; acc[1] += wj * e0.y;
                acc[2] += wj * e1.x; acc[3] += wj * e1.y;
                acc[4] += wj * e2.x; acc[5] += wj * e2.y;
                acc[6] += wj * e3.x; acc[7] += wj * e3.y;
            }
        }
        __syncthreads();
    }
#pragma unroll
    for (int off = 32; off; off >>= 1) ssum += __shfl_xor(ssum, off, 64);
    if (lane == 0) red[wave] = ssum;
    __syncthreads();
    float inv = 1.f / (red[0] + red[1] + red[2] + red[3]);

    if (act) {
        int fb = 8 * tid;
        unsigned short o[8];
#pragma unroll
        for (int t = 0; t < 8; ++t) {
            int f = fb + t;
            o[t] = f2bu((f < FOUT) ? fmaxf(acc[t] * inv + b2f(bias2[f]), 0.f) : 0.f);
        }
        uint4 pk;
        pk.x = (unsigned)o[0] | ((unsigned)o[1] << 16);
        pk.y = (unsigned)o[2] | ((unsigned)o[3] << 16);
        pk.z = (unsigned)o[4] | ((unsigned)o[5] << 16);
        pk.w = (unsigned)o[6] | ((unsigned)o[7] << 16);
        *(uint4*)(h2 + (size_t)v * KP + fb) = pk;
    }
}

// ---------------- final: out = sigmoid(H @ H^T), bf16 MFMA, 1-D triangular grid ----------------
// Round-6: LATENCY-BOUND fix.  Diagnosis across R0-R5: four schedules all land
// at 380 us / MfmaUtil 22% regardless of swizzle, phase count, occupancy, or
// traffic (fp8 halved FETCH yet ran SLOWER).  Model: per K-step the staging DMA
// latency (~400-900 cy; H > L2 agg) dwarfs the 80-cy MFMA and only ~2.5
// blocks/CU are co-resident -> MfmaUtil ~ 2.5*80/900 ~ 22% (matches).
// Fix = more outstanding staged tiles per CU: depth-3 LDS prefetch RING
// (3 slots x 8 KB x 2 mats = 48 KB -> still 3 blocks/CU) with counted vmcnt:
// stage tile kt+3 after the read-barrier; wait vmcnt(8) (FIFO => the 4 oldest
// loads = tile kt's have landed); tail kt=43 -> vmcnt(4), kt=44 -> vmcnt(0).
// Raw s_barrier (NOT __syncthreads, which drains vmcnt to 0).  Plain stores
// (R4: nt-stores RMW-inflated FETCH +300 MB).  XCD-bijective tile swizzle kept.
__global__ __launch_bounds__(256) void k_gemm_sig(const bf16_t* __restrict__ Hm,
                                                  float* __restrict__ out) {
    // XCD-bijective swizzle of the linear tile id (grid round-robins XCDs)
    int orig = blockIdx.x;
    int xcd = orig & 7, ii = orig >> 3;
    int t = (xcd == 0) ? ii : (559 + (xcd - 1) * 558 + ii);   // q=558, r=1
    // decode linear tile id -> (by, bx) with bx >= by
    int by = (int)((2 * NTILE + 1 - sqrtf((float)(2 * NTILE + 1) * (2 * NTILE + 1) - 8.0f * t)) * 0.5f);
    if (by < 0) by = 0;
    if (by > NTILE - 1) by = NTILE - 1;
    while (by + 1 < NTILE && (by + 1) * NTILE - ((by + 1) * by) / 2 <= t) ++by;
    while (by > 0 && by * NTILE - (by * (by - 1)) / 2 > t) --by;
    int bx = by + (t - (by * NTILE - (by * (by - 1)) / 2));

    __shared__ __align__(16) bf16_t As[3 * 128 * 32];   // 3-slot ring, 24 KB
    __shared__ __align__(16) bf16_t Bs[3 * 128 * 32];   // 3-slot ring, 24 KB
    const int tid = threadIdx.x;
    const int wave = tid >> 6;
    const int lane = tid & 63;
    const int rowA0 = by * 128;
    const int rowB0 = bx * 128;

    const int sRow  = wave * 16 + (lane >> 2);
    const int sSlot = (lane & 3) ^ ((lane >> 2) & 3);
    const bf16_t* gA = Hm + (size_t)(rowA0 + sRow) * KP + sSlot * 8;
    const bf16_t* gB = Hm + (size_t)(rowB0 + sRow) * KP + sSlot * 8;

    f32x4 acc[4][4] = {};

    const int wrow = wave >> 1, wcol = wave & 1;
    const int r = lane & 15, q = lane >> 4;
    const int rslot = q ^ (r & 3);
    const __bf16* Asb = (const __bf16*)As;
    const __bf16* Bsb = (const __bf16*)Bs;

// stage K-tile kt_ (BK=32) into ring slot sl_: 4 gload_lds per wave (A c0,B c0,A c1,B c1)
#define STAGE(sl_, kt_) do {                                                     \
        const int k0_ = (kt_) * 32;                                              \
        _Pragma("unroll")                                                        \
        for (int c_ = 0; c_ < 2; ++c_) {                                         \
            __builtin_amdgcn_global_load_lds(                                    \
                (const __attribute__((address_space(1))) void*)(gA + (size_t)c_ * 64 * KP + k0_), \
                (__attribute__((address_space(3))) void*)((char*)As + (sl_) * 8192 + c_ * 4096 + wave * 1024), \
                16, 0, 0);                                                       \
            __builtin_amdgcn_global_load_lds(                                    \
                (const __attribute__((address_space(1))) void*)(gB + (size_t)c_ * 64 * KP + k0_), \
                (__attribute__((address_space(3))) void*)((char*)Bs + (sl_) * 8192 + c_ * 4096 + wave * 1024), \
                16, 0, 0);                                                       \
        }                                                                        \
    } while (0)

    // prologue: fill the ring (12 loads/wave in flight)
    STAGE(0, 0); STAGE(1, 1); STAGE(2, 2);

    int sl = 0;
#pragma unroll 1
    for (int kt = 0; kt < KP / 32; ++kt) {
        // counted wait: FIFO drain to 8 leaves only tiles kt+1,kt+2 in flight
        if (kt < 43)       asm volatile("s_waitcnt vmcnt(8)" ::: "memory");
        else if (kt == 43) asm volatile("s_waitcnt vmcnt(4)" ::: "memory");
        else               asm volatile("s_waitcnt vmcnt(0)" ::: "memory");
        __builtin_amdgcn_s_barrier();          // all waves: tile kt fully in LDS
        __builtin_amdgcn_sched_barrier(0);

        bf16x8 af[4], bfr[4];
        const __bf16* Ab = Asb + sl * 4096;
        const __bf16* Bb = Bsb + sl * 4096;
#pragma unroll
        for (int mi = 0; mi < 4; ++mi)
            af[mi] = *(const bf16x8*)(Ab + ((wrow * 64 + mi * 16 + r) * 32 + rslot * 8));
#pragma unroll
        for (int ni = 0; ni < 4; ++ni)
            bfr[ni] = *(const bf16x8*)(Bb + ((wcol * 64 + ni * 16 + r) * 32 + rslot * 8));
        __builtin_amdgcn_s_setprio(1);
#pragma unroll
        for (int mi = 0; mi < 4; ++mi)
#pragma unroll
            for (int ni = 0; ni < 4; ++ni)
                acc[mi][ni] = __builtin_amdgcn_mfma_f32_16x16x32_bf16(af[mi], bfr[ni], acc[mi][ni], 0, 0, 0);
        __builtin_amdgcn_s_setprio(0);

        __builtin_amdgcn_sched_barrier(0);
        __builtin_amdgcn_s_barrier();          // all waves done reading slot sl
        if (kt + 3 < KP / 32) STAGE(sl, kt + 3);   // reuse freed slot
        sl = (sl == 2) ? 0 : sl + 1;
    }
#undef STAGE

    // epilogue. C/D layout: col=lane&15, row=(lane>>4)*4+reg. N%4==0, row0%4==0.
#pragma unroll
    for (int mi = 0; mi < 4; ++mi) {
        const int row0 = rowA0 + wrow * 64 + mi * 16 + q * 4;
#pragma unroll
        for (int ni = 0; ni < 4; ++ni) {
            const int col = rowB0 + wcol * 64 + ni * 16 + r;
            if (col < NNODES && row0 < NNODES) {
                f32x4 s;
#pragma unroll
                for (int r2 = 0; r2 < 4; ++r2)
                    s[r2] = 1.f / (1.f + __expf(-acc[mi][ni][r2]));
#pragma unroll
                for (int r2 = 0; r2 < 4; ++r2)
                    out[(size_t)(row0 + r2) * NNODES + col] = s[r2];
                if (bx != by)   // mirrored tile: contiguous float4 store
                    *(f32x4*)(out + (size_t)col * NNODES + row0) = s;
            }
        }
    }
}

extern "C" void kernel_launch(void* const* d_in, const int* in_sizes, int n_in,
                              void* d_out, int out_size, void* d_ws, size_t ws_size,
                              hipStream_t stream) {
    const bf16_t* x   = (const bf16_t*)d_in[0];
    const int*    ei  = (const int*)d_in[1];
    const bf16_t* W1  = (const bf16_t*)d_in[2];
    const bf16_t* as1 = (const bf16_t*)d_in[3];
    const bf16_t* ad1 = (const bf16_t*)d_in[4];
    const bf16_t* b1  = (const bf16_t*)d_in[5];
    const bf16_t* W2  = (const bf16_t*)d_in[6];
    const bf16_t* as2 = (const bf16_t*)d_in[7];
    const bf16_t* ad2 = (const bf16_t*)d_in[8];
    const bf16_t* b2  = (const bf16_t*)d_in[9];
    float* out = (float*)d_out;   // output 0 f32 [N][N], output 1 f32 [2][E]

    // Scratch lives inside d_out's adjacency region (576 MB f32), dead until
    // k_gemm_sig overwrites it. Only h2 (read during final GEMM) is in d_ws.
    char* obuf = (char*)d_out;
    size_t off = 0;
    auto carve = [&](size_t bytes) {
        char* p = obuf + off;
        off += (bytes + 255) & ~(size_t)255;
        return p;
    };
    float* h1pre  = (float*)carve((size_t)NNODES * FHID * 4);
    float* al1    = (float*)carve((size_t)NNODES * 4);
    float* ar1    = (float*)carve((size_t)NNODES * 4);
    float* h1     = (float*)carve((size_t)NNODES * FHID * 4);
    float* al2    = (float*)carve((size_t)NNODES * 4);
    float* ar2    = (float*)carve((size_t)NNODES * 4);
    int*   deg    = (int*)carve((size_t)NNODES * 4);
    int*   rowptr = (int*)carve((size_t)(NNODES + 1) * 4);
    int*   cursor = (int*)carve((size_t)NNODES * 4);
    int*   csrc   = (int*)carve((size_t)NETOT * 4);
    unsigned char* h2pre = (unsigned char*)carve((size_t)NNODES * KP);  // fp8
    bf16_t* h2 = (bf16_t*)d_ws;   // [MP][KP] bf16 = 34.65 MB
    (void)ws_size; (void)in_sizes; (void)n_in; (void)out_size;

    hipLaunchKernelGGL(k_init,    dim3(256), dim3(256), 0, stream, deg, h2);
    hipLaunchKernelGGL(k_count,   dim3((NEDGES + 255) / 256), dim3(256), 0, stream, ei, deg);
    hipLaunchKernelGGL(k_scan,    dim3(1), dim3(1024), 0, stream, deg, rowptr, cursor);
    hipLaunchKernelGGL(k_fill,    dim3((2 * NEDGES + 255) / 256), dim3(256), 0, stream,
                       ei, cursor, csrc, out);
    hipLaunchKernelGGL(k_linear1, dim3((NNODES + 255) / 256), dim3(256), 0, stream,
                       x, W1, as1, ad1, h1pre, al1, ar1);
    hipLaunchKernelGGL(k_agg1,    dim3(NNODES / 4), dim3(256), 0, stream,
                       h1pre, al1, ar1, rowptr, csrc, b1, h1);
    hipLaunchKernelGGL(k_linear2, dim3(NNODES / 4), dim3(256), 0, stream,
                       h1, W2, as2, ad2, h2pre, al2, ar2);
    hipLaunchKernelGGL(k_agg2,    dim3(NNODES), dim3(256), 0, stream,
                       h2pre, al2, ar2, rowptr, csrc, b2, h2);
    hipLaunchKernelGGL(k_gemm_sig, dim3(NTRI), dim3(256), 0, stream, h2, out);
}

// Round 7
// 1136.087 us; speedup vs baseline: 1.0598x; 1.0367x over previous
//
#include <hip/hip_runtime.h>
#include <hip/hip_bf16.h>

#define NNODES 12000
#define NEDGES 384000
#define NETOT  (NEDGES + NNODES)   /* 396000 incl self-loops */
#define FIN    4
#define FHID   50
#define FOUT   1433
#define KP     1440                /* FOUT padded to multiple of 32 */
#define MP     12032               /* NNODES padded to multiple of 128 */
#define NTILE  (MP / 128)          /* 94 */
#define NTRI   (NTILE * (NTILE + 1) / 2)   /* 4465 upper-triangle tiles */
#define NEG_SLOPE 0.2f

typedef __hip_bfloat16 bf16_t;
typedef __bf16 bf16x8 __attribute__((ext_vector_type(8)));
typedef float f32x4 __attribute__((ext_vector_type(4)));
typedef float f32x2 __attribute__((ext_vector_type(2)));

__device__ __forceinline__ float  b2f(bf16_t h) { return __bfloat162float(h); }
__device__ __forceinline__ bf16_t f2b(float f)  { return __float2bfloat16(f); }
__device__ __forceinline__ unsigned short f2bu(float f) { bf16_t h = f2b(f); return *(unsigned short*)&h; }

// ---------------- init: deg=1 (self loop), zero pad rows of h2 (bf16) ----------------
__global__ void k_init(int* __restrict__ deg, bf16_t* __restrict__ h2) {
    int i = blockIdx.x * blockDim.x + threadIdx.x;
    int stride = gridDim.x * blockDim.x;
    for (int v = i; v < NNODES; v += stride) deg[v] = 1;
    const size_t padN = (size_t)(MP - NNODES) * KP;
    for (size_t t = i; t < padN; t += stride) h2[(size_t)NNODES * KP + t] = f2b(0.f);
}

// ---------------- count real edges by dst ----------------
__global__ void k_count(const int* __restrict__ ei, int* __restrict__ deg) {
    int i = blockIdx.x * blockDim.x + threadIdx.x;
    if (i < NEDGES) atomicAdd(&deg[ei[NEDGES + i]], 1);
}

// ---------------- single-block shfl exclusive scan -> rowptr[N+1] + cursor[N] ----------------
__global__ __launch_bounds__(1024) void k_scan(const int* __restrict__ deg,
                                               int* __restrict__ rowptr,
                                               int* __restrict__ cursor) {
    __shared__ int wsum[16];
    const int tid = threadIdx.x, lane = tid & 63, wv = tid >> 6;
    const int base = tid * 12;
    int pref[12];
    int s = 0;
#pragma unroll
    for (int u = 0; u < 12; ++u) {
        int idx = base + u;
        int d = (idx < NNODES) ? deg[idx] : 0;
        pref[u] = s;
        s += d;
    }
    int sc = s;   // inclusive wave scan of per-thread sums
#pragma unroll
    for (int o = 1; o < 64; o <<= 1) {
        int t2 = __shfl_up(sc, o, 64);
        if (lane >= o) sc += t2;
    }
    if (lane == 63) wsum[wv] = sc;
    __syncthreads();
    if (wv == 0 && lane < 16) {
        int mine = wsum[lane];
        int scw = mine;
#pragma unroll
        for (int o = 1; o < 16; o <<= 1) {
            int t3 = __shfl_up(scw, o, 64);
            if (lane >= o) scw += t3;
        }
        wsum[lane] = scw - mine;   // exclusive wave prefix
    }
    __syncthreads();
    const int pre = wsum[wv] + (sc - s);   // exclusive prefix of this thread
#pragma unroll
    for (int u = 0; u < 12; ++u) {
        int idx = base + u;
        if (idx < NNODES) {
            int p = pre + pref[u];
            rowptr[idx] = p;
            cursor[idx] = p;
        }
    }
    if (tid == 1023) rowptr[NNODES] = pre + s;   // == NETOT
}

// ---------------- fill CSR src lists (incl self loops) + edge passthrough ----------------
__global__ void k_fill(const int* __restrict__ ei, int* __restrict__ cursor,
                       int* __restrict__ csrc, float* __restrict__ outbase) {
    int i = blockIdx.x * blockDim.x + threadIdx.x;
    if (i < NETOT) {
        int s, d;
        if (i < NEDGES) { s = ei[i]; d = ei[NEDGES + i]; }
        else            { s = d = i - NEDGES; }
        int pos = atomicAdd(&cursor[d], 1);
        csrc[pos] = s;
    }
    if (i < 2 * NEDGES)
        outbase[(size_t)NNODES * (size_t)NNODES + (size_t)i] = (float)ei[i];
}

// ---------------- layer1 linear: h1pre = x @ W1, al1/ar1 logit parts ----------------
__global__ __launch_bounds__(256) void k_linear1(
        const bf16_t* __restrict__ x, const bf16_t* __restrict__ W1,
        const bf16_t* __restrict__ as1, const bf16_t* __restrict__ ad1,
        float* __restrict__ h1pre, float* __restrict__ al, float* __restrict__ ar) {
    __shared__ float sW[FIN * FHID];
    __shared__ float sa[FHID], sdl[FHID];
    int tid = threadIdx.x;
    if (tid < FIN * FHID) sW[tid] = b2f(W1[tid]);
    if (tid < FHID) { sa[tid] = b2f(as1[tid]); sdl[tid] = b2f(ad1[tid]); }
    __syncthreads();
    int i = blockIdx.x * 256 + tid;
    if (i >= NNODES) return;
    float x0 = b2f(x[i * 4 + 0]), x1 = b2f(x[i * 4 + 1]);
    float x2 = b2f(x[i * 4 + 2]), x3 = b2f(x[i * 4 + 3]);
    float hal = 0.f, har = 0.f;
    for (int j = 0; j < FHID; ++j) {
        float h = x0 * sW[j] + x1 * sW[FHID + j] + x2 * sW[2 * FHID + j] + x3 * sW[3 * FHID + j];
        h1pre[(size_t)i * FHID + j] = h;
        hal += h * sa[j];
        har += h * sdl[j];
    }
    al[i] = hal; ar[i] = har;
}

// ---------------- layer1 softmax-aggregate: wave-per-node, no max pass, shfl broadcast ----------------
__global__ __launch_bounds__(256) void k_agg1(
        const float* __restrict__ h1pre, const float* __restrict__ al, const float* __restrict__ ar,
        const int* __restrict__ rowptr, const int* __restrict__ csrc,
        const bf16_t* __restrict__ b1, float* __restrict__ h1) {
    const int wv = threadIdx.x >> 6, lane = threadIdx.x & 63;
    const int v = blockIdx.x * 4 + wv;        // NNODES % 4 == 0
    const int s0 = rowptr[v], s1 = rowptr[v + 1];
    const float arv = ar[v];
    float acc = 0.f, ssum = 0.f;
    for (int base = s0; base < s1; base += 64) {
        int e = base + lane;
        float w = 0.f; int si = 0;
        if (e < s1) {
            si = csrc[e];
            float l = al[si] + arv;
            l = l > 0.f ? l : NEG_SLOPE * l;
            w = __expf(l);                     // softmax is shift-invariant; |l| small
        }
        ssum += w;
        int cnt = min(64, s1 - base);
#pragma unroll 4
        for (int j = 0; j < cnt; ++j) {
            float wj = __shfl(w, j, 64);
            int   sj = __shfl(si, j, 64);
            if (lane < FHID) acc += wj * h1pre[(size_t)sj * FHID + lane];
        }
    }
#pragma unroll
    for (int o = 32; o; o >>= 1) ssum += __shfl_xor(ssum, o, 64);
    if (lane < FHID) {
        float o2 = acc / ssum + b2f(b1[lane]);
        h1[(size_t)v * FHID + lane] = fmaxf(o2, 0.f);
    }
}

// ---------------- layer2 linear: 4 nodes/block, h2pre (fp8 e4m3) = h1 @ W2, al2/ar2 ----------------
__global__ __launch_bounds__(256) void k_linear2(
        const float* __restrict__ h1, const bf16_t* __restrict__ W2,
        const bf16_t* __restrict__ as2, const bf16_t* __restrict__ ad2,
        unsigned char* __restrict__ h2pre, float* __restrict__ al2, float* __restrict__ ar2) {
    int v0 = blockIdx.x * 4, tid = threadIdx.x;
    __shared__ float sh[4][FHID];
    if (tid < 4 * FHID) sh[tid / FHID][tid % FHID] = h1[(size_t)v0 * FHID + tid];
    __syncthreads();
    float pal[4] = {0.f, 0.f, 0.f, 0.f}, par[4] = {0.f, 0.f, 0.f, 0.f};
#pragma unroll
    for (int i = 0; i < 3; ++i) {
        int f0 = i * 512 + 2 * tid;          // even feature index
        if (f0 < KP) {
            float d0[4] = {0.f, 0.f, 0.f, 0.f}, d1[4] = {0.f, 0.f, 0.f, 0.f};
            bool ok0 = f0 < FOUT, ok1 = f0 + 1 < FOUT;
            if (ok0) {
                int f1 = ok1 ? f0 + 1 : f0;  // safe aliased read when f0+1 OOB
#pragma unroll 10
                for (int k = 0; k < FHID; ++k) {
                    float w0 = b2f(W2[k * FOUT + f0]);
                    float w1 = b2f(W2[k * FOUT + f1]);
#pragma unroll
                    for (int c = 0; c < 4; ++c) {
                        d0[c] += sh[c][k] * w0;
                        d1[c] += sh[c][k] * w1;
                    }
                }
                if (!ok1) { d1[0] = d1[1] = d1[2] = d1[3] = 0.f; }
                float sa0 = b2f(as2[f0]), sd0 = b2f(ad2[f0]);
                float sa1 = ok1 ? b2f(as2[f0 + 1]) : 0.f;
                float sd1 = ok1 ? b2f(ad2[f0 + 1]) : 0.f;
#pragma unroll
                for (int c = 0; c < 4; ++c) {
                    pal[c] += d0[c] * sa0 + d1[c] * sa1;
                    par[c] += d0[c] * sd0 + d1[c] * sd1;
                }
            }
#pragma unroll
            for (int c = 0; c < 4; ++c) {
                int pk = __builtin_amdgcn_cvt_pk_fp8_f32(d0[c], d1[c], 0, false);
                *(unsigned short*)(h2pre + (size_t)(v0 + c) * KP + f0) = (unsigned short)pk;
            }
        }
    }
#pragma unroll
    for (int off = 32; off; off >>= 1)
#pragma unroll
        for (int c = 0; c < 4; ++c) {
            pal[c] += __shfl_xor(pal[c], off, 64);
            par[c] += __shfl_xor(par[c], off, 64);
        }
    __shared__ float rA[4][4], rB[4][4];
    int wave = tid >> 6, lane = tid & 63;
    if (lane == 0)
#pragma unroll
        for (int c = 0; c < 4; ++c) { rA[wave][c] = pal[c]; rB[wave][c] = par[c]; }
    __syncthreads();
    if (tid < 4) {
        al2[v0 + tid] = rA[0][tid] + rA[1][tid] + rA[2][tid] + rA[3][tid];
        ar2[v0 + tid] = rB[0][tid] + rB[1][tid] + rB[2][tid] + rB[3][tid];
    }
}

// ---------------- layer2 softmax-aggregate: fp8 gather, no max pass, bf16 h2 out ----------------
__global__ __launch_bounds__(256) void k_agg2(
        const unsigned char* __restrict__ h2pre, const float* __restrict__ al, const float* __restrict__ ar,
        const int* __restrict__ rowptr, const int* __restrict__ csrc,
        const bf16_t* __restrict__ bias2, bf16_t* __restrict__ h2) {
    int v = blockIdx.x, tid = threadIdx.x;
    int s0 = rowptr[v], s1 = rowptr[v + 1];
    float arv = ar[v];
    int wave = tid >> 6, lane = tid & 63;

    float acc[8] = {0.f, 0.f, 0.f, 0.f, 0.f, 0.f, 0.f, 0.f};
    float ssum = 0.f;
    __shared__ float sw[256];
    __shared__ int ssrc[256];
    __shared__ float red[4];
    const bool act = tid < (KP / 8);          // 180 lanes cover the 1440-B row
    for (int base = s0; base < s1; base += 256) {
        int e = base + tid;
        float w = 0.f; int si = 0;
        if (e < s1) {
            si = csrc[e];
            float l = al[si] + arv;
            l = l > 0.f ? l : NEG_SLOPE * l;
            w = __expf(l);                    // shift-invariant; |l| small
        }
        ssum += w;
        sw[tid] = w; ssrc[tid] = si;
        __syncthreads();
        int cnt = min(256, s1 - base);
        if (act) {
#pragma unroll 8
            for (int j = 0; j < cnt; ++j) {
                float wj = sw[j];
                const uint2* hp = (const uint2*)(h2pre + (size_t)ssrc[j] * KP);
                uint2 p = hp[tid];
                f32x2 e0 = __builtin_amdgcn_cvt_pk_f32_fp8(p.x, false);
                f32x2 e1 = __builtin_amdgcn_cvt_pk_f32_fp8(p.x, true);
                f32x2 e2 = __builtin_amdgcn_cvt_pk_f32_fp8(p.y, false);
                f32x2 e3 = __builtin_amdgcn_cvt_pk_f32_fp8(p.y, true);
                acc[0] += wj * e0.x; acc[1] += wj * e0.y;
                acc[2] += wj * e1.x; acc[3] += wj * e1.y;
                acc[4] += wj * e2.x; acc[5] += wj * e2.y;
                acc[6] += wj * e3.x; acc[7] += wj * e3.y;
            }
        }
        __syncthreads();
    }
#pragma unroll
    for (int off = 32; off; off >>= 1) ssum += __shfl_xor(ssum, off, 64);
    if (lane == 0) red[wave] = ssum;
    __syncthreads();
    float inv = 1.f / (red[0] + red[1] + red[2] + red[3]);

    if (act) {
        int fb = 8 * tid;
        unsigned short o[8];
#pragma unroll
        for (int t = 0; t < 8; ++t) {
            int f = fb + t;
            o[t] = f2bu((f < FOUT) ? fmaxf(acc[t] * inv + b2f(bias2[f]), 0.f) : 0.f);
        }
        uint4 pk;
        pk.x = (unsigned)o[0] | ((unsigned)o[1] << 16);
        pk.y = (unsigned)o[2] | ((unsigned)o[3] << 16);
        pk.z = (unsigned)o[4] | ((unsigned)o[5] << 16);
        pk.w = (unsigned)o[6] | ((unsigned)o[7] << 16);
        *(uint4*)(h2 + (size_t)v * KP + fb) = pk;
    }
}

// ---------------- final: out = sigmoid(H @ H^T), bf16 MFMA ----------------
// Round-7: L2-LOCALITY fix.  Across R0-R6 every schedule knob nulled at ~385 us
// while FETCH_SIZE stayed at ~21% of logical panel reads: each XCD walked whole
// by-rows, so its B-panel working set (~34 MB) >> its private 4-MB L2, and the
// 576-MB write stream thrashes L3 -> 21% of staging DMAs miss to HBM (~900 cy),
// and P(a counted-vmcnt batch of 4 contains a miss) ~ 61%/K-step: un-hideable.
// Fix: GROUPED-TRIANGULAR tile order (Triton GROUP_M analog).  Tiles decoded
// bx-MAJOR within groups of 8 by-rows: per-XCD working set = 8 A-panels
// (2.9 MB) + in-flight B-panels -> ~L2-sized.  Global L3/HBM-level panel reads
// collapse 3.3 GB -> ~0.26 GB (600 B-panel fetches + A once).  Compute
// structure identical to R6: depth-3 LDS ring, counted vmcnt(8), raw
// s_barrier, setprio around MFMA, XCD-bijective chunk swizzle.
__global__ __launch_bounds__(256) void k_gemm_sig(const bf16_t* __restrict__ Hm,
                                                  float* __restrict__ out) {
    // XCD-bijective chunk swizzle (4465 = 8*558 + 1: xcd0 gets 559)
    int orig = blockIdx.x;
    int xcd = orig & 7, ii = orig >> 3;
    int tt = (xcd == 0) ? ii : (559 + (xcd - 1) * 558 + ii);

    // grouped-triangular decode: groups of 8 by-rows, bx-major inside a group
    int by0 = 88, u = tt;   // fallback = last group (never needed; loop breaks)
#pragma unroll 1
    for (int g = 0; g < 12; ++g) {
        int rows = 94 - g * 8; if (rows > 8) rows = 8;
        int T = rows * (94 - g * 8) - (rows * (rows - 1)) / 2;
        if (u < T) { by0 = g * 8; break; }
        u -= T;
    }
    const int R = (94 - by0) < 8 ? (94 - by0) : 8;
    int by, bx;
    const int tri = (R * (R + 1)) / 2;
    if (u < tri) {                      // triangular head: column c has c+1 tiles
        int c = 0;
        while (((c + 1) * (c + 2)) / 2 <= u) ++c;
        by = by0 + u - (c * (c + 1)) / 2;
        bx = by0 + c;
    } else {                            // full columns of 8 (only reachable for R==8)
        int v = u - tri;
        bx = by0 + 8 + (v >> 3);
        by = by0 + (v & 7);
    }

    __shared__ __align__(16) bf16_t As[3 * 128 * 32];   // 3-slot ring, 24 KB
    __shared__ __align__(16) bf16_t Bs[3 * 128 * 32];   // 3-slot ring, 24 KB
    const int tid = threadIdx.x;
    const int wave = tid >> 6;
    const int lane = tid & 63;
    const int rowA0 = by * 128;
    const int rowB0 = bx * 128;

    const int sRow  = wave * 16 + (lane >> 2);
    const int sSlot = (lane & 3) ^ ((lane >> 2) & 3);
    const bf16_t* gA = Hm + (size_t)(rowA0 + sRow) * KP + sSlot * 8;
    const bf16_t* gB = Hm + (size_t)(rowB0 + sRow) * KP + sSlot * 8;

    f32x4 acc[4][4] = {};

    const int wrow = wave >> 1, wcol = wave & 1;
    const int r = lane & 15, q = lane >> 4;
    const int rslot = q ^ (r & 3);
    const __bf16* Asb = (const __bf16*)As;
    const __bf16* Bsb = (const __bf16*)Bs;

// stage K-tile kt_ (BK=32) into ring slot sl_: 4 gload_lds per wave
#define STAGE(sl_, kt_) do {                                                     \
        const int k0_ = (kt_) * 32;                                              \
        _Pragma("unroll")                                                        \
        for (int c_ = 0; c_ < 2; ++c_) {                                         \
            __builtin_amdgcn_global_load_lds(                                    \
                (const __attribute__((address_space(1))) void*)(gA + (size_t)c_ * 64 * KP + k0_), \
                (__attribute__((address_space(3))) void*)((char*)As + (sl_) * 8192 + c_ * 4096 + wave * 1024), \
                16, 0, 0);                                                       \
            __builtin_amdgcn_global_load_lds(                                    \
                (const __attribute__((address_space(1))) void*)(gB + (size_t)c_ * 64 * KP + k0_), \
                (__attribute__((address_space(3))) void*)((char*)Bs + (sl_) * 8192 + c_ * 4096 + wave * 1024), \
                16, 0, 0);                                                       \
        }                                                                        \
    } while (0)

    // prologue: fill the ring (12 loads/wave in flight)
    STAGE(0, 0); STAGE(1, 1); STAGE(2, 2);

    int sl = 0;
#pragma unroll 1
    for (int kt = 0; kt < KP / 32; ++kt) {
        // counted wait: FIFO drain to 8 => tile kt's 4 loads have landed
        if (kt < 43)       asm volatile("s_waitcnt vmcnt(8)" ::: "memory");
        else if (kt == 43) asm volatile("s_waitcnt vmcnt(4)" ::: "memory");
        else               asm volatile("s_waitcnt vmcnt(0)" ::: "memory");
        __builtin_amdgcn_s_barrier();          // all waves: tile kt fully in LDS
        __builtin_amdgcn_sched_barrier(0);

        bf16x8 af[4], bfr[4];
        const __bf16* Ab = Asb + sl * 4096;
        const __bf16* Bb = Bsb + sl * 4096;
#pragma unroll
        for (int mi = 0; mi < 4; ++mi)
            af[mi] = *(const bf16x8*)(Ab + ((wrow * 64 + mi * 16 + r) * 32 + rslot * 8));
#pragma unroll
        for (int ni = 0; ni < 4; ++ni)
            bfr[ni] = *(const bf16x8*)(Bb + ((wcol * 64 + ni * 16 + r) * 32 + rslot * 8));
        __builtin_amdgcn_s_setprio(1);
#pragma unroll
        for (int mi = 0; mi < 4; ++mi)
#pragma unroll
            for (int ni = 0; ni < 4; ++ni)
                acc[mi][ni] = __builtin_amdgcn_mfma_f32_16x16x32_bf16(af[mi], bfr[ni], acc[mi][ni], 0, 0, 0);
        __builtin_amdgcn_s_setprio(0);

        __builtin_amdgcn_sched_barrier(0);
        __builtin_amdgcn_s_barrier();          // all waves done reading slot sl
        if (kt + 3 < KP / 32) STAGE(sl, kt + 3);   // reuse freed slot
        sl = (sl == 2) ? 0 : sl + 1;
    }
#undef STAGE

    // epilogue. C/D layout: col=lane&15, row=(lane>>4)*4+reg. N%4==0, row0%4==0.
#pragma unroll
    for (int mi = 0; mi < 4; ++mi) {
        const int row0 = rowA0 + wrow * 64 + mi * 16 + q * 4;
#pragma unroll
        for (int ni = 0; ni < 4; ++ni) {
            const int col = rowB0 + wcol * 64 + ni * 16 + r;
            if (col < NNODES && row0 < NNODES) {
                f32x4 s;
#pragma unroll
                for (int r2 = 0; r2 < 4; ++r2)
                    s[r2] = 1.f / (1.f + __expf(-acc[mi][ni][r2]));
#pragma unroll
                for (int r2 = 0; r2 < 4; ++r2)
                    out[(size_t)(row0 + r2) * NNODES + col] = s[r2];
                if (bx != by)   // mirrored tile: contiguous float4 store
                    *(f32x4*)(out + (size_t)col * NNODES + row0) = s;
            }
        }
    }
}

extern "C" void kernel_launch(void* const* d_in, const int* in_sizes, int n_in,
                              void* d_out, int out_size, void* d_ws, size_t ws_size,
                              hipStream_t stream) {
    const bf16_t* x   = (const bf16_t*)d_in[0];
    const int*    ei  = (const int*)d_in[1];
    const bf16_t* W1  = (const bf16_t*)d_in[2];
    const bf16_t* as1 = (const bf16_t*)d_in[3];
    const bf16_t* ad1 = (const bf16_t*)d_in[4];
    const bf16_t* b1  = (const bf16_t*)d_in[5];
    const bf16_t* W2  = (const bf16_t*)d_in[6];
    const bf16_t* as2 = (const bf16_t*)d_in[7];
    const bf16_t* ad2 = (const bf16_t*)d_in[8];
    const bf16_t* b2  = (const bf16_t*)d_in[9];
    float* out = (float*)d_out;   // output 0 f32 [N][N], output 1 f32 [2][E]

    // Scratch lives inside d_out's adjacency region (576 MB f32), dead until
    // k_gemm_sig overwrites it. Only h2 (read during final GEMM) is in d_ws.
    char* obuf = (char*)d_out;
    size_t off = 0;
    auto carve = [&](size_t bytes) {
        char* p = obuf + off;
        off += (bytes + 255) & ~(size_t)255;
        return p;
    };
    float* h1pre  = (float*)carve((size_t)NNODES * FHID * 4);
    float* al1    = (float*)carve((size_t)NNODES * 4);
    float* ar1    = (float*)carve((size_t)NNODES * 4);
    float* h1     = (float*)carve((size_t)NNODES * FHID * 4);
    float* al2    = (float*)carve((size_t)NNODES * 4);
    float* ar2    = (float*)carve((size_t)NNODES * 4);
    int*   deg    = (int*)carve((size_t)NNODES * 4);
    int*   rowptr = (int*)carve((size_t)(NNODES + 1) * 4);
    int*   cursor = (int*)carve((size_t)NNODES * 4);
    int*   csrc   = (int*)carve((size_t)NETOT * 4);
    unsigned char* h2pre = (unsigned char*)carve((size_t)NNODES * KP);  // fp8
    bf16_t* h2 = (bf16_t*)d_ws;   // [MP][KP] bf16 = 34.65 MB
    (void)ws_size; (void)in_sizes; (void)n_in; (void)out_size;

    hipLaunchKernelGGL(k_init,    dim3(256), dim3(256), 0, stream, deg, h2);
    hipLaunchKernelGGL(k_count,   dim3((NEDGES + 255) / 256), dim3(256), 0, stream, ei, deg);
    hipLaunchKernelGGL(k_scan,    dim3(1), dim3(1024), 0, stream, deg, rowptr, cursor);
    hipLaunchKernelGGL(k_fill,    dim3((2 * NEDGES + 255) / 256), dim3(256), 0, stream,
                       ei, cursor, csrc, out);
    hipLaunchKernelGGL(k_linear1, dim3((NNODES + 255) / 256), dim3(256), 0, stream,
                       x, W1, as1, ad1, h1pre, al1, ar1);
    hipLaunchKernelGGL(k_agg1,    dim3(NNODES / 4), dim3(256), 0, stream,
                       h1pre, al1, ar1, rowptr, csrc, b1, h1);
    hipLaunchKernelGGL(k_linear2, dim3(NNODES / 4), dim3(256), 0, stream,
                       h1, W2, as2, ad2, h2pre, al2, ar2);
    hipLaunchKernelGGL(k_agg2,    dim3(NNODES), dim3(256), 0, stream,
                       h2pre, al2, ar2, rowptr, csrc, b2, h2);
    hipLaunchKernelGGL(k_gemm_sig, dim3(NTRI), dim3(256), 0, stream, h2, out);
}

// Round 8
// 1121.647 us; speedup vs baseline: 1.0734x; 1.0129x over previous
//
#include <hip/hip_runtime.h>
#include <hip/hip_bf16.h>

#define NNODES 12000
#define NEDGES 384000
#define NETOT  (NEDGES + NNODES)   /* 396000 incl self-loops */
#define FIN    4
#define FHID   50
#define FOUT   1433
#define KP     1440                /* FOUT padded to multiple of 32 */
#define MP     12032               /* NNODES padded to multiple of 256 */
#define GT     (MP / 256)          /* 47 tiles of 256 */
#define GTRI   (GT * (GT + 1) / 2) /* 1128 upper-triangle tiles = 8*141 */
#define NEG_SLOPE 0.2f

typedef __hip_bfloat16 bf16_t;
typedef __bf16 bf16x8 __attribute__((ext_vector_type(8)));
typedef float f32x4 __attribute__((ext_vector_type(4)));
typedef float f32x2 __attribute__((ext_vector_type(2)));

__device__ __forceinline__ float  b2f(bf16_t h) { return __bfloat162float(h); }
__device__ __forceinline__ bf16_t f2b(float f)  { return __float2bfloat16(f); }
__device__ __forceinline__ unsigned short f2bu(float f) { bf16_t h = f2b(f); return *(unsigned short*)&h; }

// ---------------- init: deg=1 (self loop), zero pad rows of h2 (bf16) ----------------
__global__ void k_init(int* __restrict__ deg, bf16_t* __restrict__ h2) {
    int i = blockIdx.x * blockDim.x + threadIdx.x;
    int stride = gridDim.x * blockDim.x;
    for (int v = i; v < NNODES; v += stride) deg[v] = 1;
    const size_t padN = (size_t)(MP - NNODES) * KP;
    for (size_t t = i; t < padN; t += stride) h2[(size_t)NNODES * KP + t] = f2b(0.f);
}

// ---------------- count real edges by dst ----------------
__global__ void k_count(const int* __restrict__ ei, int* __restrict__ deg) {
    int i = blockIdx.x * blockDim.x + threadIdx.x;
    if (i < NEDGES) atomicAdd(&deg[ei[NEDGES + i]], 1);
}

// ---------------- single-block shfl exclusive scan -> rowptr[N+1] + cursor[N] ----------------
__global__ __launch_bounds__(1024) void k_scan(const int* __restrict__ deg,
                                               int* __restrict__ rowptr,
                                               int* __restrict__ cursor) {
    __shared__ int wsum[16];
    const int tid = threadIdx.x, lane = tid & 63, wv = tid >> 6;
    const int base = tid * 12;
    int pref[12];
    int s = 0;
#pragma unroll
    for (int u = 0; u < 12; ++u) {
        int idx = base + u;
        int d = (idx < NNODES) ? deg[idx] : 0;
        pref[u] = s;
        s += d;
    }
    int sc = s;   // inclusive wave scan of per-thread sums
#pragma unroll
    for (int o = 1; o < 64; o <<= 1) {
        int t2 = __shfl_up(sc, o, 64);
        if (lane >= o) sc += t2;
    }
    if (lane == 63) wsum[wv] = sc;
    __syncthreads();
    if (wv == 0 && lane < 16) {
        int mine = wsum[lane];
        int scw = mine;
#pragma unroll
        for (int o = 1; o < 16; o <<= 1) {
            int t3 = __shfl_up(scw, o, 64);
            if (lane >= o) scw += t3;
        }
        wsum[lane] = scw - mine;   // exclusive wave prefix
    }
    __syncthreads();
    const int pre = wsum[wv] + (sc - s);   // exclusive prefix of this thread
#pragma unroll
    for (int u = 0; u < 12; ++u) {
        int idx = base + u;
        if (idx < NNODES) {
            int p = pre + pref[u];
            rowptr[idx] = p;
            cursor[idx] = p;
        }
    }
    if (tid == 1023) rowptr[NNODES] = pre + s;   // == NETOT
}

// ---------------- fill CSR src lists (incl self loops) + edge passthrough ----------------
__global__ void k_fill(const int* __restrict__ ei, int* __restrict__ cursor,
                       int* __restrict__ csrc, float* __restrict__ outbase) {
    int i = blockIdx.x * blockDim.x + threadIdx.x;
    if (i < NETOT) {
        int s, d;
        if (i < NEDGES) { s = ei[i]; d = ei[NEDGES + i]; }
        else            { s = d = i - NEDGES; }
        int pos = atomicAdd(&cursor[d], 1);
        csrc[pos] = s;
    }
    if (i < 2 * NEDGES)
        outbase[(size_t)NNODES * (size_t)NNODES + (size_t)i] = (float)ei[i];
}

// ---------------- layer1 linear: h1pre = x @ W1, al1/ar1 logit parts ----------------
__global__ __launch_bounds__(256) void k_linear1(
        const bf16_t* __restrict__ x, const bf16_t* __restrict__ W1,
        const bf16_t* __restrict__ as1, const bf16_t* __restrict__ ad1,
        float* __restrict__ h1pre, float* __restrict__ al, float* __restrict__ ar) {
    __shared__ float sW[FIN * FHID];
    __shared__ float sa[FHID], sdl[FHID];
    int tid = threadIdx.x;
    if (tid < FIN * FHID) sW[tid] = b2f(W1[tid]);
    if (tid < FHID) { sa[tid] = b2f(as1[tid]); sdl[tid] = b2f(ad1[tid]); }
    __syncthreads();
    int i = blockIdx.x * 256 + tid;
    if (i >= NNODES) return;
    float x0 = b2f(x[i * 4 + 0]), x1 = b2f(x[i * 4 + 1]);
    float x2 = b2f(x[i * 4 + 2]), x3 = b2f(x[i * 4 + 3]);
    float hal = 0.f, har = 0.f;
    for (int j = 0; j < FHID; ++j) {
        float h = x0 * sW[j] + x1 * sW[FHID + j] + x2 * sW[2 * FHID + j] + x3 * sW[3 * FHID + j];
        h1pre[(size_t)i * FHID + j] = h;
        hal += h * sa[j];
        har += h * sdl[j];
    }
    al[i] = hal; ar[i] = har;
}

// ---------------- layer1 softmax-aggregate ----------------
__global__ __launch_bounds__(256) void k_agg1(
        const float* __restrict__ h1pre, const float* __restrict__ al, const float* __restrict__ ar,
        const int* __restrict__ rowptr, const int* __restrict__ csrc,
        const bf16_t* __restrict__ b1, float* __restrict__ h1) {
    const int wv = threadIdx.x >> 6, lane = threadIdx.x & 63;
    const int v = blockIdx.x * 4 + wv;        // NNODES % 4 == 0
    const int s0 = rowptr[v], s1 = rowptr[v + 1];
    const float arv = ar[v];
    float acc = 0.f, ssum = 0.f;
    for (int base = s0; base < s1; base += 64) {
        int e = base + lane;
        float w = 0.f; int si = 0;
        if (e < s1) {
            si = csrc[e];
            float l = al[si] + arv;
            l = l > 0.f ? l : NEG_SLOPE * l;
            w = __expf(l);                     // softmax is shift-invariant; |l| small
        }
        ssum += w;
        int cnt = min(64, s1 - base);
#pragma unroll 4
        for (int j = 0; j < cnt; ++j) {
            float wj = __shfl(w, j, 64);
            int   sj = __shfl(si, j, 64);
            if (lane < FHID) acc += wj * h1pre[(size_t)sj * FHID + lane];
        }
    }
#pragma unroll
    for (int o = 32; o; o >>= 1) ssum += __shfl_xor(ssum, o, 64);
    if (lane < FHID) {
        float o2 = acc / ssum + b2f(b1[lane]);
        h1[(size_t)v * FHID + lane] = fmaxf(o2, 0.f);
    }
}

// ---------------- layer2 linear: 4 nodes/block, h2pre (fp8 e4m3) = h1 @ W2, al2/ar2 ----------------
__global__ __launch_bounds__(256) void k_linear2(
        const float* __restrict__ h1, const bf16_t* __restrict__ W2,
        const bf16_t* __restrict__ as2, const bf16_t* __restrict__ ad2,
        unsigned char* __restrict__ h2pre, float* __restrict__ al2, float* __restrict__ ar2) {
    int v0 = blockIdx.x * 4, tid = threadIdx.x;
    __shared__ float sh[4][FHID];
    if (tid < 4 * FHID) sh[tid / FHID][tid % FHID] = h1[(size_t)v0 * FHID + tid];
    __syncthreads();
    float pal[4] = {0.f, 0.f, 0.f, 0.f}, par[4] = {0.f, 0.f, 0.f, 0.f};
#pragma unroll
    for (int i = 0; i < 3; ++i) {
        int f0 = i * 512 + 2 * tid;          // even feature index
        if (f0 < KP) {
            float d0[4] = {0.f, 0.f, 0.f, 0.f}, d1[4] = {0.f, 0.f, 0.f, 0.f};
            bool ok0 = f0 < FOUT, ok1 = f0 + 1 < FOUT;
            if (ok0) {
                int f1 = ok1 ? f0 + 1 : f0;  // safe aliased read when f0+1 OOB
#pragma unroll 10
                for (int k = 0; k < FHID; ++k) {
                    float w0 = b2f(W2[k * FOUT + f0]);
                    float w1 = b2f(W2[k * FOUT + f1]);
#pragma unroll
                    for (int c = 0; c < 4; ++c) {
                        d0[c] += sh[c][k] * w0;
                        d1[c] += sh[c][k] * w1;
                    }
                }
                if (!ok1) { d1[0] = d1[1] = d1[2] = d1[3] = 0.f; }
                float sa0 = b2f(as2[f0]), sd0 = b2f(ad2[f0]);
                float sa1 = ok1 ? b2f(as2[f0 + 1]) : 0.f;
                float sd1 = ok1 ? b2f(ad2[f0 + 1]) : 0.f;
#pragma unroll
                for (int c = 0; c < 4; ++c) {
                    pal[c] += d0[c] * sa0 + d1[c] * sa1;
                    par[c] += d0[c] * sd0 + d1[c] * sd1;
                }
            }
#pragma unroll
            for (int c = 0; c < 4; ++c) {
                int pk = __builtin_amdgcn_cvt_pk_fp8_f32(d0[c], d1[c], 0, false);
                *(unsigned short*)(h2pre + (size_t)(v0 + c) * KP + f0) = (unsigned short)pk;
            }
        }
    }
#pragma unroll
    for (int off = 32; off; off >>= 1)
#pragma unroll
        for (int c = 0; c < 4; ++c) {
            pal[c] += __shfl_xor(pal[c], off, 64);
            par[c] += __shfl_xor(par[c], off, 64);
        }
    __shared__ float rA[4][4], rB[4][4];
    int wave = tid >> 6, lane = tid & 63;
    if (lane == 0)
#pragma unroll
        for (int c = 0; c < 4; ++c) { rA[wave][c] = pal[c]; rB[wave][c] = par[c]; }
    __syncthreads();
    if (tid < 4) {
        al2[v0 + tid] = rA[0][tid] + rA[1][tid] + rA[2][tid] + rA[3][tid];
        ar2[v0 + tid] = rB[0][tid] + rB[1][tid] + rB[2][tid] + rB[3][tid];
    }
}

// ---------------- layer2 softmax-aggregate: fp8 gather, no max pass, bf16 h2 out ----------------
__global__ __launch_bounds__(256) void k_agg2(
        const unsigned char* __restrict__ h2pre, const float* __restrict__ al, const float* __restrict__ ar,
        const int* __restrict__ rowptr, const int* __restrict__ csrc,
        const bf16_t* __restrict__ bias2, bf16_t* __restrict__ h2) {
    int v = blockIdx.x, tid = threadIdx.x;
    int s0 = rowptr[v], s1 = rowptr[v + 1];
    float arv = ar[v];
    int wave = tid >> 6, lane = tid & 63;

    float acc[8] = {0.f, 0.f, 0.f, 0.f, 0.f, 0.f, 0.f, 0.f};
    float ssum = 0.f;
    __shared__ float sw[256];
    __shared__ int ssrc[256];
    __shared__ float red[4];
    const bool act = tid < (KP / 8);          // 180 lanes cover the 1440-B row
    for (int base = s0; base < s1; base += 256) {
        int e = base + tid;
        float w = 0.f; int si = 0;
        if (e < s1) {
            si = csrc[e];
            float l = al[si] + arv;
            l = l > 0.f ? l : NEG_SLOPE * l;
            w = __expf(l);                    // shift-invariant; |l| small
        }
        ssum += w;
        sw[tid] = w; ssrc[tid] = si;
        __syncthreads();
        int cnt = min(256, s1 - base);
        if (act) {
#pragma unroll 8
            for (int j = 0; j < cnt; ++j) {
                float wj = sw[j];
                const uint2* hp = (const uint2*)(h2pre + (size_t)ssrc[j] * KP);
                uint2 p = hp[tid];
                f32x2 e0 = __builtin_amdgcn_cvt_pk_f32_fp8(p.x, false);
                f32x2 e1 = __builtin_amdgcn_cvt_pk_f32_fp8(p.x, true);
                f32x2 e2 = __builtin_amdgcn_cvt_pk_f32_fp8(p.y, false);
                f32x2 e3 = __builtin_amdgcn_cvt_pk_f32_fp8(p.y, true);
                acc[0] += wj * e0.x; acc[1] += wj * e0.y;
                acc[2] += wj * e1.x; acc[3] += wj * e1.y;
                acc[4] += wj * e2.x; acc[5] += wj * e2.y;
                acc[6] += wj * e3.x; acc[7] += wj * e3.y;
            }
        }
        __syncthreads();
    }
#pragma unroll
    for (int off = 32; off; off >>= 1) ssum += __shfl_xor(ssum, off, 64);
    if (lane == 0) red[wave] = ssum;
    __syncthreads();
    float inv = 1.f / (red[0] + red[1] + red[2] + red[3]);

    if (act) {
        int fb = 8 * tid;
        unsigned short o[8];
#pragma unroll
        for (int t = 0; t < 8; ++t) {
            int f = fb + t;
            o[t] = f2bu((f < FOUT) ? fmaxf(acc[t] * inv + b2f(bias2[f]), 0.f) : 0.f);
        }
        uint4 pk;
        pk.x = (unsigned)o[0] | ((unsigned)o[1] << 16);
        pk.y = (unsigned)o[2] | ((unsigned)o[3] << 16);
        pk.z = (unsigned)o[4] | ((unsigned)o[5] << 16);
        pk.w = (unsigned)o[6] | ((unsigned)o[7] << 16);
        *(uint4*)(h2 + (size_t)v * KP + fb) = pk;
    }
}

// ---------------- final: out = sigmoid(H @ H^T), 8-phase 256x256 MFMA GEMM ----------------
// Round-8 = R3's verified 8-phase body + R7's grouped locality.
// Cross-round synthesis: every 2-phase variant (R0/R1/R2/R4/R5/R6/R7) ran at
// the documented ~600-TF 2-phase ceiling (350-390 us).  The one 8-phase try
// (R3) nulled because 21% of its staging DMAs missed L2 to HBM (~900 cy) --
// more than its prefetch cover -- with 1 block/CU and no TLP.  R7's grouped
// tile order fixed exactly that (per-XCD working set ~3 MB < 4 MB L2, first
// measured GEMM gain).  This round: 8-phase 256x256 (BK=64, K-half staging at
// 64-B rows = conflict-free linear LDS, counted vmcnt(4), raw s_barriers,
// setprio around MFMA) + grouped-triangular decode (G=4 by-rows, bx-major) +
// XCD-bijective chunk swizzle (1128 = 8*141).
__global__ __launch_bounds__(512, 2) void k_gemm_sig(const bf16_t* __restrict__ Hm,
                                                     float* __restrict__ out) {
    // XCD-bijective chunk swizzle
    int orig = blockIdx.x;
    int tt = (orig & 7) * (GTRI / 8) + (orig >> 3);

    // grouped-triangular decode: groups of 4 by-rows, bx-major inside a group
    int by0 = 44, u = tt;
#pragma unroll 1
    for (int g = 0; g < 12; ++g) {
        int rows = GT - g * 4; if (rows > 4) rows = 4;
        int T = rows * (GT - g * 4) - (rows * (rows - 1)) / 2;
        if (u < T) { by0 = g * 4; break; }
        u -= T;
    }
    const int R = (GT - by0) < 4 ? (GT - by0) : 4;
    int by, bx;
    const int tri = (R * (R + 1)) / 2;
    if (u < tri) {                      // triangular head: column c has c+1 tiles
        int c = 0;
        while (((c + 1) * (c + 2)) / 2 <= u) ++c;
        by = by0 + u - (c * (c + 1)) / 2;
        bx = by0 + c;
    } else {                            // full columns of R (R==4 when reachable)
        int v = u - tri;
        bx = by0 + R + (v >> 2);
        by = by0 + (v & 3);
    }

    __shared__ __align__(16) char lds[131072];

    const int tid  = threadIdx.x;
    const int wave = tid >> 6, lane = tid & 63;
    const int rowA0 = by * 256, rowB0 = bx * 256;
    const int wr = wave >> 2, wc = wave & 3;    // 2M x 4N wave grid
    const int r = lane & 15, q4 = lane >> 4;

    // staging source: linear byte index within a 16 KB K-half -> (row, col)
    const int lin  = wave * 1024 + lane * 16;        // 0..8191 (second load adds 8192)
    const int grow = lin >> 6;                       // 0..127
    const int gcol = (lin & 63) >> 1;                // element col 0..31
    const bf16_t* gAs = Hm + (size_t)(rowA0 + grow) * KP + gcol;
    const bf16_t* gBs = Hm + (size_t)(rowB0 + grow) * KP + gcol;

    // fragment read offsets within a K-half (row stride 64 B)
    const int aOff = (wr * 128 + r) * 64 + q4 * 16;
    const int bOff = (wc * 64  + r) * 64 + q4 * 16;

    f32x4 acc[8][4] = {};
    bf16x8 af[4], bfr[4];

// stage one K-half (kh: 0=A-ks0, 1=B-ks0, 2=A-ks1, 3=B-ks1) of K-tile kt_ into slot ns_
#define STAGE_KH(ns_, kt_, kh_) do {                                             \
        const bf16_t* gs_ = ((kh_) & 1) ? gBs : gAs;                             \
        char* ld_ = lds + (ns_) * 65536 + ((kh_) & 1) * 32768                    \
                        + ((kh_) >> 1) * 16384 + wave * 1024;                    \
        const int kc_ = (kt_) * 64 + ((kh_) >> 1) * 32;                          \
        __builtin_amdgcn_global_load_lds(                                        \
            (const __attribute__((address_space(1))) void*)(gs_ + kc_),          \
            (__attribute__((address_space(3))) void*)ld_, 16, 0, 0);             \
        __builtin_amdgcn_global_load_lds(                                        \
            (const __attribute__((address_space(1))) void*)(gs_ + kc_ + (size_t)128 * KP), \
            (__attribute__((address_space(3))) void*)(ld_ + 8192), 16, 0, 0);    \
    } while (0)

#define LOAD_BFR(Bb_, ks_) { _Pragma("unroll") for (int n_ = 0; n_ < 4; ++n_)    \
        bfr[n_] = *(const bf16x8*)((Bb_) + (ks_) * 16384 + bOff + n_ * 1024); }
#define LOAD_AF(Ab_, ks_, mh_) { _Pragma("unroll") for (int m_ = 0; m_ < 4; ++m_) \
        af[m_] = *(const bf16x8*)((Ab_) + (ks_) * 16384 + aOff + (mh_) * 4096 + m_ * 1024); }

#define MFMA16(mh_) {                                                            \
        __builtin_amdgcn_s_setprio(1);                                           \
        _Pragma("unroll") for (int m_ = 0; m_ < 4; ++m_)                         \
        _Pragma("unroll") for (int n_ = 0; n_ < 4; ++n_)                         \
            acc[(mh_) * 4 + m_][n_] = __builtin_amdgcn_mfma_f32_16x16x32_bf16(   \
                af[m_], bfr[n_], acc[(mh_) * 4 + m_][n_], 0, 0, 0);              \
        __builtin_amdgcn_s_setprio(0); }

#define SYNC_PRE()  { __builtin_amdgcn_s_barrier();                              \
        asm volatile("s_waitcnt lgkmcnt(0)" ::: "memory");                       \
        __builtin_amdgcn_sched_barrier(0); }
#define SYNC_POST() { __builtin_amdgcn_sched_barrier(0); __builtin_amdgcn_s_barrier(); }

    // prologue: stage tile 0 fully; leave its last 2 K-halves in flight
    STAGE_KH(0, 0, 0); STAGE_KH(0, 0, 1); STAGE_KH(0, 0, 2); STAGE_KH(0, 0, 3);
    asm volatile("s_waitcnt vmcnt(4)" ::: "memory");
    __builtin_amdgcn_s_barrier();

#pragma unroll 1
    for (int t = 0; t < 22; ++t) {
        const int sl = t & 1, ns = sl ^ 1;
        const char* Ab = lds + sl * 65536;
        const char* Bb = lds + sl * 65536 + 32768;
        const bool st = (t < 21);
        // phase 0: ks=0, mi 0-3
        LOAD_BFR(Bb, 0); LOAD_AF(Ab, 0, 0);
        if (st) STAGE_KH(ns, t + 1, 0);
        SYNC_PRE(); MFMA16(0); SYNC_POST();
        // phase 1: ks=0, mi 4-7   [vmcnt guards next phase's A/B ks=1 reads]
        LOAD_AF(Ab, 0, 1);
        if (st) { STAGE_KH(ns, t + 1, 1); asm volatile("s_waitcnt vmcnt(4)" ::: "memory"); }
        else    { asm volatile("s_waitcnt vmcnt(0)" ::: "memory"); }
        SYNC_PRE(); MFMA16(1); SYNC_POST();
        // phase 2: ks=1, mi 0-3
        LOAD_BFR(Bb, 1); LOAD_AF(Ab, 1, 0);
        if (st) STAGE_KH(ns, t + 1, 2);
        SYNC_PRE(); MFMA16(0); SYNC_POST();
        // phase 3: ks=1, mi 4-7   [vmcnt guards next tile's phase-0 reads]
        LOAD_AF(Ab, 1, 1);
        if (st) { STAGE_KH(ns, t + 1, 3); asm volatile("s_waitcnt vmcnt(4)" ::: "memory"); }
        SYNC_PRE(); MFMA16(1); SYNC_POST();
    }
#undef STAGE_KH

    // K tail: columns 1408..1439, fragments straight from global (H is L2-hot)
    {
        bf16x8 at[8], bt[4];
#pragma unroll
        for (int mi = 0; mi < 8; ++mi)
            at[mi] = *(const bf16x8*)(Hm + (size_t)(rowA0 + wr * 128 + mi * 16 + r) * KP + 1408 + q4 * 8);
#pragma unroll
        for (int ni = 0; ni < 4; ++ni)
            bt[ni] = *(const bf16x8*)(Hm + (size_t)(rowB0 + wc * 64 + ni * 16 + r) * KP + 1408 + q4 * 8);
#pragma unroll
        for (int mi = 0; mi < 8; ++mi)
#pragma unroll
            for (int ni = 0; ni < 4; ++ni)
                acc[mi][ni] = __builtin_amdgcn_mfma_f32_16x16x32_bf16(at[mi], bt[ni], acc[mi][ni], 0, 0, 0);
    }

    // epilogue. C/D layout: col=lane&15, row=(lane>>4)*4+reg. NNODES%4==0.
#pragma unroll
    for (int mi = 0; mi < 8; ++mi) {
        const int row0 = rowA0 + wr * 128 + mi * 16 + q4 * 4;
#pragma unroll
        for (int ni = 0; ni < 4; ++ni) {
            const int col = rowB0 + wc * 64 + ni * 16 + r;
            if (col < NNODES && row0 < NNODES) {
                f32x4 s;
#pragma unroll
                for (int r2 = 0; r2 < 4; ++r2)
                    s[r2] = 1.f / (1.f + __expf(-acc[mi][ni][r2]));
#pragma unroll
                for (int r2 = 0; r2 < 4; ++r2)
                    out[(size_t)(row0 + r2) * NNODES + col] = s[r2];
                if (bx != by)   // mirrored tile: contiguous float4 store
                    *(f32x4*)(out + (size_t)col * NNODES + row0) = s;
            }
        }
    }
}

extern "C" void kernel_launch(void* const* d_in, const int* in_sizes, int n_in,
                              void* d_out, int out_size, void* d_ws, size_t ws_size,
                              hipStream_t stream) {
    const bf16_t* x   = (const bf16_t*)d_in[0];
    const int*    ei  = (const int*)d_in[1];
    const bf16_t* W1  = (const bf16_t*)d_in[2];
    const bf16_t* as1 = (const bf16_t*)d_in[3];
    const bf16_t* ad1 = (const bf16_t*)d_in[4];
    const bf16_t* b1  = (const bf16_t*)d_in[5];
    const bf16_t* W2  = (const bf16_t*)d_in[6];
    const bf16_t* as2 = (const bf16_t*)d_in[7];
    const bf16_t* ad2 = (const bf16_t*)d_in[8];
    const bf16_t* b2  = (const bf16_t*)d_in[9];
    float* out = (float*)d_out;   // output 0 f32 [N][N], output 1 f32 [2][E]

    // Scratch lives inside d_out's adjacency region (576 MB f32), dead until
    // k_gemm_sig overwrites it. Only h2 (read during final GEMM) is in d_ws.
    char* obuf = (char*)d_out;
    size_t off = 0;
    auto carve = [&](size_t bytes) {
        char* p = obuf + off;
        off += (bytes + 255) & ~(size_t)255;
        return p;
    };
    float* h1pre  = (float*)carve((size_t)NNODES * FHID * 4);
    float* al1    = (float*)carve((size_t)NNODES * 4);
    float* ar1    = (float*)carve((size_t)NNODES * 4);
    float* h1     = (float*)carve((size_t)NNODES * FHID * 4);
    float* al2    = (float*)carve((size_t)NNODES * 4);
    float* ar2    = (float*)carve((size_t)NNODES * 4);
    int*   deg    = (int*)carve((size_t)NNODES * 4);
    int*   rowptr = (int*)carve((size_t)(NNODES + 1) * 4);
    int*   cursor = (int*)carve((size_t)NNODES * 4);
    int*   csrc   = (int*)carve((size_t)NETOT * 4);
    unsigned char* h2pre = (unsigned char*)carve((size_t)NNODES * KP);  // fp8
    bf16_t* h2 = (bf16_t*)d_ws;   // [MP][KP] bf16 = 34.65 MB
    (void)ws_size; (void)in_sizes; (void)n_in; (void)out_size;

    hipLaunchKernelGGL(k_init,    dim3(256), dim3(256), 0, stream, deg, h2);
    hipLaunchKernelGGL(k_count,   dim3((NEDGES + 255) / 256), dim3(256), 0, stream, ei, deg);
    hipLaunchKernelGGL(k_scan,    dim3(1), dim3(1024), 0, stream, deg, rowptr, cursor);
    hipLaunchKernelGGL(k_fill,    dim3((2 * NEDGES + 255) / 256), dim3(256), 0, stream,
                       ei, cursor, csrc, out);
    hipLaunchKernelGGL(k_linear1, dim3((NNODES + 255) / 256), dim3(256), 0, stream,
                       x, W1, as1, ad1, h1pre, al1, ar1);
    hipLaunchKernelGGL(k_agg1,    dim3(NNODES / 4), dim3(256), 0, stream,
                       h1pre, al1, ar1, rowptr, csrc, b1, h1);
    hipLaunchKernelGGL(k_linear2, dim3(NNODES / 4), dim3(256), 0, stream,
                       h1, W2, as2, ad2, h2pre, al2, ar2);
    hipLaunchKernelGGL(k_agg2,    dim3(NNODES), dim3(256), 0, stream,
                       h2pre, al2, ar2, rowptr, csrc, b2, h2);
    hipLaunchKernelGGL(k_gemm_sig, dim3(GTRI), dim3(512), 0, stream, h2, out);
}

// Round 9
// 1093.992 us; speedup vs baseline: 1.1006x; 1.0253x over previous
//
#include <hip/hip_runtime.h>
#include <hip/hip_bf16.h>

#define NNODES 12000
#define NEDGES 384000
#define NETOT  (NEDGES + NNODES)   /* 396000 incl self-loops */
#define FIN    4
#define FHID   50
#define FOUT   1433
#define KP     1440                /* FOUT padded to multiple of 32 */
#define MP     12032               /* NNODES padded: 94*128 = 47*256 */
#define GRID_G 2256                /* rect-tri tiles 128x256: sum(47 - (by>>1)) = 8*282 */
#define NEG_SLOPE 0.2f

typedef __hip_bfloat16 bf16_t;
typedef __bf16 bf16x8 __attribute__((ext_vector_type(8)));
typedef float f32x4 __attribute__((ext_vector_type(4)));
typedef float f32x2 __attribute__((ext_vector_type(2)));

__device__ __forceinline__ float  b2f(bf16_t h) { return __bfloat162float(h); }
__device__ __forceinline__ bf16_t f2b(float f)  { return __float2bfloat16(f); }
__device__ __forceinline__ unsigned short f2bu(float f) { bf16_t h = f2b(f); return *(unsigned short*)&h; }

// ---------------- init: deg=1 (self loop), zero pad rows of h2 (bf16) ----------------
__global__ void k_init(int* __restrict__ deg, bf16_t* __restrict__ h2) {
    int i = blockIdx.x * blockDim.x + threadIdx.x;
    int stride = gridDim.x * blockDim.x;
    for (int v = i; v < NNODES; v += stride) deg[v] = 1;
    const size_t padN = (size_t)(MP - NNODES) * KP;
    for (size_t t = i; t < padN; t += stride) h2[(size_t)NNODES * KP + t] = f2b(0.f);
}

// ---------------- count real edges by dst ----------------
__global__ void k_count(const int* __restrict__ ei, int* __restrict__ deg) {
    int i = blockIdx.x * blockDim.x + threadIdx.x;
    if (i < NEDGES) atomicAdd(&deg[ei[NEDGES + i]], 1);
}

// ---------------- single-block shfl exclusive scan -> rowptr[N+1] + cursor[N] ----------------
__global__ __launch_bounds__(1024) void k_scan(const int* __restrict__ deg,
                                               int* __restrict__ rowptr,
                                               int* __restrict__ cursor) {
    __shared__ int wsum[16];
    const int tid = threadIdx.x, lane = tid & 63, wv = tid >> 6;
    const int base = tid * 12;
    int pref[12];
    int s = 0;
#pragma unroll
    for (int u = 0; u < 12; ++u) {
        int idx = base + u;
        int d = (idx < NNODES) ? deg[idx] : 0;
        pref[u] = s;
        s += d;
    }
    int sc = s;   // inclusive wave scan of per-thread sums
#pragma unroll
    for (int o = 1; o < 64; o <<= 1) {
        int t2 = __shfl_up(sc, o, 64);
        if (lane >= o) sc += t2;
    }
    if (lane == 63) wsum[wv] = sc;
    __syncthreads();
    if (wv == 0 && lane < 16) {
        int mine = wsum[lane];
        int scw = mine;
#pragma unroll
        for (int o = 1; o < 16; o <<= 1) {
            int t3 = __shfl_up(scw, o, 64);
            if (lane >= o) scw += t3;
        }
        wsum[lane] = scw - mine;   // exclusive wave prefix
    }
    __syncthreads();
    const int pre = wsum[wv] + (sc - s);   // exclusive prefix of this thread
#pragma unroll
    for (int u = 0; u < 12; ++u) {
        int idx = base + u;
        if (idx < NNODES) {
            int p = pre + pref[u];
            rowptr[idx] = p;
            cursor[idx] = p;
        }
    }
    if (tid == 1023) rowptr[NNODES] = pre + s;   // == NETOT
}

// ---------------- fill CSR src lists (incl self loops) + edge passthrough ----------------
__global__ void k_fill(const int* __restrict__ ei, int* __restrict__ cursor,
                       int* __restrict__ csrc, float* __restrict__ outbase) {
    int i = blockIdx.x * blockDim.x + threadIdx.x;
    if (i < NETOT) {
        int s, d;
        if (i < NEDGES) { s = ei[i]; d = ei[NEDGES + i]; }
        else            { s = d = i - NEDGES; }
        int pos = atomicAdd(&cursor[d], 1);
        csrc[pos] = s;
    }
    if (i < 2 * NEDGES)
        outbase[(size_t)NNODES * (size_t)NNODES + (size_t)i] = (float)ei[i];
}

// ---------------- layer1 linear: h1pre = x @ W1, al1/ar1 logit parts ----------------
__global__ __launch_bounds__(256) void k_linear1(
        const bf16_t* __restrict__ x, const bf16_t* __restrict__ W1,
        const bf16_t* __restrict__ as1, const bf16_t* __restrict__ ad1,
        float* __restrict__ h1pre, float* __restrict__ al, float* __restrict__ ar) {
    __shared__ float sW[FIN * FHID];
    __shared__ float sa[FHID], sdl[FHID];
    int tid = threadIdx.x;
    if (tid < FIN * FHID) sW[tid] = b2f(W1[tid]);
    if (tid < FHID) { sa[tid] = b2f(as1[tid]); sdl[tid] = b2f(ad1[tid]); }
    __syncthreads();
    int i = blockIdx.x * 256 + tid;
    if (i >= NNODES) return;
    float x0 = b2f(x[i * 4 + 0]), x1 = b2f(x[i * 4 + 1]);
    float x2 = b2f(x[i * 4 + 2]), x3 = b2f(x[i * 4 + 3]);
    float hal = 0.f, har = 0.f;
    for (int j = 0; j < FHID; ++j) {
        float h = x0 * sW[j] + x1 * sW[FHID + j] + x2 * sW[2 * FHID + j] + x3 * sW[3 * FHID + j];
        h1pre[(size_t)i * FHID + j] = h;
        hal += h * sa[j];
        har += h * sdl[j];
    }
    al[i] = hal; ar[i] = har;
}

// ---------------- layer1 softmax-aggregate ----------------
__global__ __launch_bounds__(256) void k_agg1(
        const float* __restrict__ h1pre, const float* __restrict__ al, const float* __restrict__ ar,
        const int* __restrict__ rowptr, const int* __restrict__ csrc,
        const bf16_t* __restrict__ b1, float* __restrict__ h1) {
    const int wv = threadIdx.x >> 6, lane = threadIdx.x & 63;
    const int v = blockIdx.x * 4 + wv;        // NNODES % 4 == 0
    const int s0 = rowptr[v], s1 = rowptr[v + 1];
    const float arv = ar[v];
    float acc = 0.f, ssum = 0.f;
    for (int base = s0; base < s1; base += 64) {
        int e = base + lane;
        float w = 0.f; int si = 0;
        if (e < s1) {
            si = csrc[e];
            float l = al[si] + arv;
            l = l > 0.f ? l : NEG_SLOPE * l;
            w = __expf(l);                     // softmax is shift-invariant; |l| small
        }
        ssum += w;
        int cnt = min(64, s1 - base);
#pragma unroll 4
        for (int j = 0; j < cnt; ++j) {
            float wj = __shfl(w, j, 64);
            int   sj = __shfl(si, j, 64);
            if (lane < FHID) acc += wj * h1pre[(size_t)sj * FHID + lane];
        }
    }
#pragma unroll
    for (int o = 32; o; o >>= 1) ssum += __shfl_xor(ssum, o, 64);
    if (lane < FHID) {
        float o2 = acc / ssum + b2f(b1[lane]);
        h1[(size_t)v * FHID + lane] = fmaxf(o2, 0.f);
    }
}

// ---------------- layer2 linear: 4 nodes/block, h2pre (fp8 e4m3) = h1 @ W2, al2/ar2 ----------------
__global__ __launch_bounds__(256) void k_linear2(
        const float* __restrict__ h1, const bf16_t* __restrict__ W2,
        const bf16_t* __restrict__ as2, const bf16_t* __restrict__ ad2,
        unsigned char* __restrict__ h2pre, float* __restrict__ al2, float* __restrict__ ar2) {
    int v0 = blockIdx.x * 4, tid = threadIdx.x;
    __shared__ float sh[4][FHID];
    if (tid < 4 * FHID) sh[tid / FHID][tid % FHID] = h1[(size_t)v0 * FHID + tid];
    __syncthreads();
    float pal[4] = {0.f, 0.f, 0.f, 0.f}, par[4] = {0.f, 0.f, 0.f, 0.f};
#pragma unroll
    for (int i = 0; i < 3; ++i) {
        int f0 = i * 512 + 2 * tid;          // even feature index
        if (f0 < KP) {
            float d0[4] = {0.f, 0.f, 0.f, 0.f}, d1[4] = {0.f, 0.f, 0.f, 0.f};
            bool ok0 = f0 < FOUT, ok1 = f0 + 1 < FOUT;
            if (ok0) {
                int f1 = ok1 ? f0 + 1 : f0;  // safe aliased read when f0+1 OOB
#pragma unroll 10
                for (int k = 0; k < FHID; ++k) {
                    float w0 = b2f(W2[k * FOUT + f0]);
                    float w1 = b2f(W2[k * FOUT + f1]);
#pragma unroll
                    for (int c = 0; c < 4; ++c) {
                        d0[c] += sh[c][k] * w0;
                        d1[c] += sh[c][k] * w1;
                    }
                }
                if (!ok1) { d1[0] = d1[1] = d1[2] = d1[3] = 0.f; }
                float sa0 = b2f(as2[f0]), sd0 = b2f(ad2[f0]);
                float sa1 = ok1 ? b2f(as2[f0 + 1]) : 0.f;
                float sd1 = ok1 ? b2f(ad2[f0 + 1]) : 0.f;
#pragma unroll
                for (int c = 0; c < 4; ++c) {
                    pal[c] += d0[c] * sa0 + d1[c] * sa1;
                    par[c] += d0[c] * sd0 + d1[c] * sd1;
                }
            }
#pragma unroll
            for (int c = 0; c < 4; ++c) {
                int pk = __builtin_amdgcn_cvt_pk_fp8_f32(d0[c], d1[c], 0, false);
                *(unsigned short*)(h2pre + (size_t)(v0 + c) * KP + f0) = (unsigned short)pk;
            }
        }
    }
#pragma unroll
    for (int off = 32; off; off >>= 1)
#pragma unroll
        for (int c = 0; c < 4; ++c) {
            pal[c] += __shfl_xor(pal[c], off, 64);
            par[c] += __shfl_xor(par[c], off, 64);
        }
    __shared__ float rA[4][4], rB[4][4];
    int wave = tid >> 6, lane = tid & 63;
    if (lane == 0)
#pragma unroll
        for (int c = 0; c < 4; ++c) { rA[wave][c] = pal[c]; rB[wave][c] = par[c]; }
    __syncthreads();
    if (tid < 4) {
        al2[v0 + tid] = rA[0][tid] + rA[1][tid] + rA[2][tid] + rA[3][tid];
        ar2[v0 + tid] = rB[0][tid] + rB[1][tid] + rB[2][tid] + rB[3][tid];
    }
}

// ---------------- layer2 softmax-aggregate: fp8 gather, no max pass, bf16 h2 out ----------------
__global__ __launch_bounds__(256) void k_agg2(
        const unsigned char* __restrict__ h2pre, const float* __restrict__ al, const float* __restrict__ ar,
        const int* __restrict__ rowptr, const int* __restrict__ csrc,
        const bf16_t* __restrict__ bias2, bf16_t* __restrict__ h2) {
    int v = blockIdx.x, tid = threadIdx.x;
    int s0 = rowptr[v], s1 = rowptr[v + 1];
    float arv = ar[v];
    int wave = tid >> 6, lane = tid & 63;

    float acc[8] = {0.f, 0.f, 0.f, 0.f, 0.f, 0.f, 0.f, 0.f};
    float ssum = 0.f;
    __shared__ float sw[256];
    __shared__ int ssrc[256];
    __shared__ float red[4];
    const bool act = tid < (KP / 8);          // 180 lanes cover the 1440-B row
    for (int base = s0; base < s1; base += 256) {
        int e = base + tid;
        float w = 0.f; int si = 0;
        if (e < s1) {
            si = csrc[e];
            float l = al[si] + arv;
            l = l > 0.f ? l : NEG_SLOPE * l;
            w = __expf(l);                    // shift-invariant; |l| small
        }
        ssum += w;
        sw[tid] = w; ssrc[tid] = si;
        __syncthreads();
        int cnt = min(256, s1 - base);
        if (act) {
#pragma unroll 8
            for (int j = 0; j < cnt; ++j) {
                float wj = sw[j];
                const uint2* hp = (const uint2*)(h2pre + (size_t)ssrc[j] * KP);
                uint2 p = hp[tid];
                f32x2 e0 = __builtin_amdgcn_cvt_pk_f32_fp8(p.x, false);
                f32x2 e1 = __builtin_amdgcn_cvt_pk_f32_fp8(p.x, true);
                f32x2 e2 = __builtin_amdgcn_cvt_pk_f32_fp8(p.y, false);
                f32x2 e3 = __builtin_amdgcn_cvt_pk_f32_fp8(p.y, true);
                acc[0] += wj * e0.x; acc[1] += wj * e0.y;
                acc[2] += wj * e1.x; acc[3] += wj * e1.y;
                acc[4] += wj * e2.x; acc[5] += wj * e2.y;
                acc[6] += wj * e3.x; acc[7] += wj * e3.y;
            }
        }
        __syncthreads();
    }
#pragma unroll
    for (int off = 32; off; off >>= 1) ssum += __shfl_xor(ssum, off, 64);
    if (lane == 0) red[wave] = ssum;
    __syncthreads();
    float inv = 1.f / (red[0] + red[1] + red[2] + red[3]);

    if (act) {
        int fb = 8 * tid;
        unsigned short o[8];
#pragma unroll
        for (int t = 0; t < 8; ++t) {
            int f = fb + t;
            o[t] = f2bu((f < FOUT) ? fmaxf(acc[t] * inv + b2f(bias2[f]), 0.f) : 0.f);
        }
        uint4 pk;
        pk.x = (unsigned)o[0] | ((unsigned)o[1] << 16);
        pk.y = (unsigned)o[2] | ((unsigned)o[3] << 16);
        pk.z = (unsigned)o[4] | ((unsigned)o[5] << 16);
        pk.w = (unsigned)o[6] | ((unsigned)o[7] << 16);
        *(uint4*)(h2 + (size_t)v * KP + fb) = pk;
    }
}

// ---------------- final: out = sigmoid(H @ H^T), 128x256 MFMA GEMM ----------------
// Round-9: write/compute-overlap geometry.  R8 proved the 256^2 tile is VGPR-
// capped to 1 block/CU (acc[8][4]+frags ~ 200 regs -> 2 waves/SIMD), so the
// 579-MB output stream (92-100 us at achievable BW) SERIALIZES with compute.
// 128x256 tile, 4 waves (1Mx4N, per-wave 128x64 out, acc[8][4]), BK=32:
// block = 256 thr -> at <=256 VGPR this is 2 blocks/CU (8 waves), LDS =
// 3-slot ring x 24 KB = 72 KB -> 144 KB/CU.  Two blocks overlap each other's
// epilogue writes, barrier stalls, and staging misses.  K = 45*32 exactly (no
// tail).  Counted vmcnt(12) (6 loads/step, depth-3 ring, FIFO: drain-to-12
// lands step t; tail 12->6->0).  2 raw s_barriers/step (90 total).  Rect-
// triangular coverage: tiles (by 0..93, bx >= by>>1) = 2256 = 8*282 exactly;
// symmetric double-writes on diagonal-crossing tiles are value-identical.
// Grouped decode (8 by-rows, bx-major: A-WS 2.88 MB + B-panel < 4 MB L2) +
// XCD-bijective chunking.
__global__ __launch_bounds__(256, 2) void k_gemm_sig(const bf16_t* __restrict__ Hm,
                                                     float* __restrict__ out) {
    // XCD-bijective chunk swizzle (2256 = 8*282)
    int orig = blockIdx.x;
    int tt = (orig & 7) * (GRID_G / 8) + (orig >> 3);

    // grouped decode: groups of 8 by-rows (last 6), bx-major inside a group
    int u = tt, by0 = 88, R = 6;
#pragma unroll 1
    for (int g = 0; g < 12; ++g) {
        int Rg = (g == 11) ? 6 : 8;
        int sz = (g == 11) ? 12 : (364 - 32 * g);
        if (u < sz) { by0 = 8 * g; R = Rg; break; }
        u -= sz;
    }
    int d = 0;
#pragma unroll 1
    for (;;) {
        int s = 2 * d + 2; if (s > R) s = R;
        if (u < s) break;
        u -= s; ++d;
    }
    const int by = by0 + u;
    const int bx = (by0 >> 1) + d;

    __shared__ __align__(16) char lds[3 * 24576];   // ring: A 8KB + B 16KB per slot

    const int tid  = threadIdx.x;
    const int wave = tid >> 6, lane = tid & 63;
    const int rowA0 = by * 128;          // C rows
    const int colC0 = bx * 256;          // C cols = B rows
    const int r = lane & 15, q4 = lane >> 4;

    // staging source: thread covers 16 B at (row = c*64 + tid>>2, elem col = (tid&3)*8)
    const int srow = tid >> 2, scol = (tid & 3) * 8;
    const bf16_t* gA = Hm + (size_t)(rowA0 + srow) * KP + scol;
    const bf16_t* gB = Hm + (size_t)(colC0 + srow) * KP + scol;

    // fragment read offsets (row stride 64 B within a slot)
    const int aOff = r * 64 + q4 * 16;                       // + mi*1024
    const int bOff = 8192 + (wave * 64 + r) * 64 + q4 * 16;  // + ni*1024

    f32x4 acc[8][4] = {};

// stage K-step kt_ into ring slot sl_: 6 gload_lds per thread-group (2 A + 4 B)
#define STAGE(sl_, kt_) do {                                                      \
        const int k0_ = (kt_) * 32;                                               \
        char* base_ = lds + (sl_) * 24576;                                        \
        _Pragma("unroll")                                                         \
        for (int c_ = 0; c_ < 2; ++c_)                                            \
            __builtin_amdgcn_global_load_lds(                                     \
                (const __attribute__((address_space(1))) void*)(gA + (size_t)(c_ * 64) * KP + k0_), \
                (__attribute__((address_space(3))) void*)(base_ + c_ * 4096 + wave * 1024 + (lane & 63) * 16), \
                16, 0, 0);                                                        \
        _Pragma("unroll")                                                         \
        for (int c_ = 0; c_ < 4; ++c_)                                            \
            __builtin_amdgcn_global_load_lds(                                     \
                (const __attribute__((address_space(1))) void*)(gB + (size_t)(c_ * 64) * KP + k0_), \
                (__attribute__((address_space(3))) void*)(base_ + 8192 + c_ * 4096 + wave * 1024 + (lane & 63) * 16), \
                16, 0, 0);                                                        \
    } while (0)

    // prologue: fill the ring (18 loads in flight)
    STAGE(0, 0); STAGE(1, 1); STAGE(2, 2);

    int sl = 0;
#pragma unroll 1
    for (int kt = 0; kt < 45; ++kt) {
        if (kt < 43)       asm volatile("s_waitcnt vmcnt(12)" ::: "memory");
        else if (kt == 43) asm volatile("s_waitcnt vmcnt(6)"  ::: "memory");
        else               asm volatile("s_waitcnt vmcnt(0)"  ::: "memory");
        __builtin_amdgcn_s_barrier();          // all waves: step kt fully in LDS
        __builtin_amdgcn_sched_barrier(0);

        const char* S = lds + sl * 24576;
        bf16x8 bfr[4], af[4];
#pragma unroll
        for (int ni = 0; ni < 4; ++ni)
            bfr[ni] = *(const bf16x8*)(S + bOff + ni * 1024);
        // half 1: mi 0-3
#pragma unroll
        for (int mi = 0; mi < 4; ++mi)
            af[mi] = *(const bf16x8*)(S + aOff + mi * 1024);
        __builtin_amdgcn_s_setprio(1);
#pragma unroll
        for (int mi = 0; mi < 4; ++mi)
#pragma unroll
            for (int ni = 0; ni < 4; ++ni)
                acc[mi][ni] = __builtin_amdgcn_mfma_f32_16x16x32_bf16(af[mi], bfr[ni], acc[mi][ni], 0, 0, 0);
        __builtin_amdgcn_s_setprio(0);
        // half 2: mi 4-7
#pragma unroll
        for (int mi = 0; mi < 4; ++mi)
            af[mi] = *(const bf16x8*)(S + aOff + (mi + 4) * 1024);
        __builtin_amdgcn_s_setprio(1);
#pragma unroll
        for (int mi = 0; mi < 4; ++mi)
#pragma unroll
            for (int ni = 0; ni < 4; ++ni)
                acc[mi + 4][ni] = __builtin_amdgcn_mfma_f32_16x16x32_bf16(af[mi], bfr[ni], acc[mi + 4][ni], 0, 0, 0);
        __builtin_amdgcn_s_setprio(0);

        __builtin_amdgcn_sched_barrier(0);
        __builtin_amdgcn_s_barrier();          // all waves done reading slot sl
        if (kt + 3 < 45) STAGE(sl, kt + 3);    // reuse freed slot
        sl = (sl == 2) ? 0 : sl + 1;
    }
#undef STAGE

    // epilogue. C/D layout: col=lane&15, row=(lane>>4)*4+reg. NNODES%4==0.
    // Direct store + unconditional mirror store (overlaps write equal values).
#pragma unroll
    for (int mi = 0; mi < 8; ++mi) {
        const int row0 = rowA0 + mi * 16 + q4 * 4;
#pragma unroll
        for (int ni = 0; ni < 4; ++ni) {
            const int col = colC0 + wave * 64 + ni * 16 + r;
            if (col < NNODES && row0 < NNODES) {
                f32x4 s;
#pragma unroll
                for (int r2 = 0; r2 < 4; ++r2)
                    s[r2] = 1.f / (1.f + __expf(-acc[mi][ni][r2]));
#pragma unroll
                for (int r2 = 0; r2 < 4; ++r2)
                    out[(size_t)(row0 + r2) * NNODES + col] = s[r2];
                *(f32x4*)(out + (size_t)col * NNODES + row0) = s;   // mirror
            }
        }
    }
}

extern "C" void kernel_launch(void* const* d_in, const int* in_sizes, int n_in,
                              void* d_out, int out_size, void* d_ws, size_t ws_size,
                              hipStream_t stream) {
    const bf16_t* x   = (const bf16_t*)d_in[0];
    const int*    ei  = (const int*)d_in[1];
    const bf16_t* W1  = (const bf16_t*)d_in[2];
    const bf16_t* as1 = (const bf16_t*)d_in[3];
    const bf16_t* ad1 = (const bf16_t*)d_in[4];
    const bf16_t* b1  = (const bf16_t*)d_in[5];
    const bf16_t* W2  = (const bf16_t*)d_in[6];
    const bf16_t* as2 = (const bf16_t*)d_in[7];
    const bf16_t* ad2 = (const bf16_t*)d_in[8];
    const bf16_t* b2  = (const bf16_t*)d_in[9];
    float* out = (float*)d_out;   // output 0 f32 [N][N], output 1 f32 [2][E]

    // Scratch lives inside d_out's adjacency region (576 MB f32), dead until
    // k_gemm_sig overwrites it. Only h2 (read during final GEMM) is in d_ws.
    char* obuf = (char*)d_out;
    size_t off = 0;
    auto carve = [&](size_t bytes) {
        char* p = obuf + off;
        off += (bytes + 255) & ~(size_t)255;
        return p;
    };
    float* h1pre  = (float*)carve((size_t)NNODES * FHID * 4);
    float* al1    = (float*)carve((size_t)NNODES * 4);
    float* ar1    = (float*)carve((size_t)NNODES * 4);
    float* h1     = (float*)carve((size_t)NNODES * FHID * 4);
    float* al2    = (float*)carve((size_t)NNODES * 4);
    float* ar2    = (float*)carve((size_t)NNODES * 4);
    int*   deg    = (int*)carve((size_t)NNODES * 4);
    int*   rowptr = (int*)carve((size_t)(NNODES + 1) * 4);
    int*   cursor = (int*)carve((size_t)NNODES * 4);
    int*   csrc   = (int*)carve((size_t)NETOT * 4);
    unsigned char* h2pre = (unsigned char*)carve((size_t)NNODES * KP);  // fp8
    bf16_t* h2 = (bf16_t*)d_ws;   // [MP][KP] bf16 = 34.65 MB
    (void)ws_size; (void)in_sizes; (void)n_in; (void)out_size;

    hipLaunchKernelGGL(k_init,    dim3(256), dim3(256), 0, stream, deg, h2);
    hipLaunchKernelGGL(k_count,   dim3((NEDGES + 255) / 256), dim3(256), 0, stream, ei, deg);
    hipLaunchKernelGGL(k_scan,    dim3(1), dim3(1024), 0, stream, deg, rowptr, cursor);
    hipLaunchKernelGGL(k_fill,    dim3((2 * NEDGES + 255) / 256), dim3(256), 0, stream,
                       ei, cursor, csrc, out);
    hipLaunchKernelGGL(k_linear1, dim3((NNODES + 255) / 256), dim3(256), 0, stream,
                       x, W1, as1, ad1, h1pre, al1, ar1);
    hipLaunchKernelGGL(k_agg1,    dim3(NNODES / 4), dim3(256), 0, stream,
                       h1pre, al1, ar1, rowptr, csrc, b1, h1);
    hipLaunchKernelGGL(k_linear2, dim3(NNODES / 4), dim3(256), 0, stream,
                       h1, W2, as2, ad2, h2pre, al2, ar2);
    hipLaunchKernelGGL(k_agg2,    dim3(NNODES), dim3(256), 0, stream,
                       h2pre, al2, ar2, rowptr, csrc, b2, h2);
    hipLaunchKernelGGL(k_gemm_sig, dim3(GRID_G), dim3(256), 0, stream, h2, out);
}

// Round 10
// 1093.801 us; speedup vs baseline: 1.1008x; 1.0002x over previous
//
#include <hip/hip_runtime.h>
#include <hip/hip_bf16.h>

#define NNODES 12000
#define NEDGES 384000
#define NETOT  (NEDGES + NNODES)   /* 396000 incl self-loops */
#define FIN    4
#define FHID   50
#define FOUT   1433
#define KP     1440                /* FOUT padded to multiple of 32 */
#define MP     12032               /* NNODES padded: 94*128 = 47*256 */
#define GRID_G 2256                /* rect-tri tiles 128x256: sum(47 - (by>>1)) = 8*282 */
#define NEG_SLOPE 0.2f

typedef __hip_bfloat16 bf16_t;
typedef __bf16 bf16x8 __attribute__((ext_vector_type(8)));
typedef float f32x4 __attribute__((ext_vector_type(4)));
typedef float f32x2 __attribute__((ext_vector_type(2)));

__device__ __forceinline__ float  b2f(bf16_t h) { return __bfloat162float(h); }
__device__ __forceinline__ bf16_t f2b(float f)  { return __float2bfloat16(f); }
__device__ __forceinline__ unsigned short f2bu(float f) { bf16_t h = f2b(f); return *(unsigned short*)&h; }

// ---------------- init: deg=1 (self loop), zero pad rows of h2 (bf16) ----------------
__global__ void k_init(int* __restrict__ deg, bf16_t* __restrict__ h2) {
    int i = blockIdx.x * blockDim.x + threadIdx.x;
    int stride = gridDim.x * blockDim.x;
    for (int v = i; v < NNODES; v += stride) deg[v] = 1;
    const size_t padN = (size_t)(MP - NNODES) * KP;
    for (size_t t = i; t < padN; t += stride) h2[(size_t)NNODES * KP + t] = f2b(0.f);
}

// ---------------- count real edges by dst ----------------
__global__ void k_count(const int* __restrict__ ei, int* __restrict__ deg) {
    int i = blockIdx.x * blockDim.x + threadIdx.x;
    if (i < NEDGES) atomicAdd(&deg[ei[NEDGES + i]], 1);
}

// ---------------- single-block shfl exclusive scan -> rowptr[N+1] + cursor[N] ----------------
__global__ __launch_bounds__(1024) void k_scan(const int* __restrict__ deg,
                                               int* __restrict__ rowptr,
                                               int* __restrict__ cursor) {
    __shared__ int wsum[16];
    const int tid = threadIdx.x, lane = tid & 63, wv = tid >> 6;
    const int base = tid * 12;
    int pref[12];
    int s = 0;
#pragma unroll
    for (int u = 0; u < 12; ++u) {
        int idx = base + u;
        int d = (idx < NNODES) ? deg[idx] : 0;
        pref[u] = s;
        s += d;
    }
    int sc = s;   // inclusive wave scan of per-thread sums
#pragma unroll
    for (int o = 1; o < 64; o <<= 1) {
        int t2 = __shfl_up(sc, o, 64);
        if (lane >= o) sc += t2;
    }
    if (lane == 63) wsum[wv] = sc;
    __syncthreads();
    if (wv == 0 && lane < 16) {
        int mine = wsum[lane];
        int scw = mine;
#pragma unroll
        for (int o = 1; o < 16; o <<= 1) {
            int t3 = __shfl_up(scw, o, 64);
            if (lane >= o) scw += t3;
        }
        wsum[lane] = scw - mine;   // exclusive wave prefix
    }
    __syncthreads();
    const int pre = wsum[wv] + (sc - s);   // exclusive prefix of this thread
#pragma unroll
    for (int u = 0; u < 12; ++u) {
        int idx = base + u;
        if (idx < NNODES) {
            int p = pre + pref[u];
            rowptr[idx] = p;
            cursor[idx] = p;
        }
    }
    if (tid == 1023) rowptr[NNODES] = pre + s;   // == NETOT
}

// ---------------- fill CSR src lists (incl self loops) + edge passthrough ----------------
__global__ void k_fill(const int* __restrict__ ei, int* __restrict__ cursor,
                       int* __restrict__ csrc, float* __restrict__ outbase) {
    int i = blockIdx.x * blockDim.x + threadIdx.x;
    if (i < NETOT) {
        int s, d;
        if (i < NEDGES) { s = ei[i]; d = ei[NEDGES + i]; }
        else            { s = d = i - NEDGES; }
        int pos = atomicAdd(&cursor[d], 1);
        csrc[pos] = s;
    }
    if (i < 2 * NEDGES)
        outbase[(size_t)NNODES * (size_t)NNODES + (size_t)i] = (float)ei[i];
}

// ---------------- layer1 linear: h1pre = x @ W1, al1/ar1 logit parts ----------------
__global__ __launch_bounds__(256) void k_linear1(
        const bf16_t* __restrict__ x, const bf16_t* __restrict__ W1,
        const bf16_t* __restrict__ as1, const bf16_t* __restrict__ ad1,
        float* __restrict__ h1pre, float* __restrict__ al, float* __restrict__ ar) {
    __shared__ float sW[FIN * FHID];
    __shared__ float sa[FHID], sdl[FHID];
    int tid = threadIdx.x;
    if (tid < FIN * FHID) sW[tid] = b2f(W1[tid]);
    if (tid < FHID) { sa[tid] = b2f(as1[tid]); sdl[tid] = b2f(ad1[tid]); }
    __syncthreads();
    int i = blockIdx.x * 256 + tid;
    if (i >= NNODES) return;
    float x0 = b2f(x[i * 4 + 0]), x1 = b2f(x[i * 4 + 1]);
    float x2 = b2f(x[i * 4 + 2]), x3 = b2f(x[i * 4 + 3]);
    float hal = 0.f, har = 0.f;
    for (int j = 0; j < FHID; ++j) {
        float h = x0 * sW[j] + x1 * sW[FHID + j] + x2 * sW[2 * FHID + j] + x3 * sW[3 * FHID + j];
        h1pre[(size_t)i * FHID + j] = h;
        hal += h * sa[j];
        har += h * sdl[j];
    }
    al[i] = hal; ar[i] = har;
}

// ---------------- layer1 softmax-aggregate ----------------
__global__ __launch_bounds__(256) void k_agg1(
        const float* __restrict__ h1pre, const float* __restrict__ al, const float* __restrict__ ar,
        const int* __restrict__ rowptr, const int* __restrict__ csrc,
        const bf16_t* __restrict__ b1, float* __restrict__ h1) {
    const int wv = threadIdx.x >> 6, lane = threadIdx.x & 63;
    const int v = blockIdx.x * 4 + wv;        // NNODES % 4 == 0
    const int s0 = rowptr[v], s1 = rowptr[v + 1];
    const float arv = ar[v];
    float acc = 0.f, ssum = 0.f;
    for (int base = s0; base < s1; base += 64) {
        int e = base + lane;
        float w = 0.f; int si = 0;
        if (e < s1) {
            si = csrc[e];
            float l = al[si] + arv;
            l = l > 0.f ? l : NEG_SLOPE * l;
            w = __expf(l);                     // softmax is shift-invariant; |l| small
        }
        ssum += w;
        int cnt = min(64, s1 - base);
#pragma unroll 4
        for (int j = 0; j < cnt; ++j) {
            float wj = __shfl(w, j, 64);
            int   sj = __shfl(si, j, 64);
            if (lane < FHID) acc += wj * h1pre[(size_t)sj * FHID + lane];
        }
    }
#pragma unroll
    for (int o = 32; o; o >>= 1) ssum += __shfl_xor(ssum, o, 64);
    if (lane < FHID) {
        float o2 = acc / ssum + b2f(b1[lane]);
        h1[(size_t)v * FHID + lane] = fmaxf(o2, 0.f);
    }
}

// ---------------- layer2 linear: 4 nodes/block, h2pre (fp8 e4m3) = h1 @ W2, al2/ar2 ----------------
__global__ __launch_bounds__(256) void k_linear2(
        const float* __restrict__ h1, const bf16_t* __restrict__ W2,
        const bf16_t* __restrict__ as2, const bf16_t* __restrict__ ad2,
        unsigned char* __restrict__ h2pre, float* __restrict__ al2, float* __restrict__ ar2) {
    int v0 = blockIdx.x * 4, tid = threadIdx.x;
    __shared__ float sh[4][FHID];
    if (tid < 4 * FHID) sh[tid / FHID][tid % FHID] = h1[(size_t)v0 * FHID + tid];
    __syncthreads();
    float pal[4] = {0.f, 0.f, 0.f, 0.f}, par[4] = {0.f, 0.f, 0.f, 0.f};
#pragma unroll
    for (int i = 0; i < 3; ++i) {
        int f0 = i * 512 + 2 * tid;          // even feature index
        if (f0 < KP) {
            float d0[4] = {0.f, 0.f, 0.f, 0.f}, d1[4] = {0.f, 0.f, 0.f, 0.f};
            bool ok0 = f0 < FOUT, ok1 = f0 + 1 < FOUT;
            if (ok0) {
                int f1 = ok1 ? f0 + 1 : f0;  // safe aliased read when f0+1 OOB
#pragma unroll 10
                for (int k = 0; k < FHID; ++k) {
                    float w0 = b2f(W2[k * FOUT + f0]);
                    float w1 = b2f(W2[k * FOUT + f1]);
#pragma unroll
                    for (int c = 0; c < 4; ++c) {
                        d0[c] += sh[c][k] * w0;
                        d1[c] += sh[c][k] * w1;
                    }
                }
                if (!ok1) { d1[0] = d1[1] = d1[2] = d1[3] = 0.f; }
                float sa0 = b2f(as2[f0]), sd0 = b2f(ad2[f0]);
                float sa1 = ok1 ? b2f(as2[f0 + 1]) : 0.f;
                float sd1 = ok1 ? b2f(ad2[f0 + 1]) : 0.f;
#pragma unroll
                for (int c = 0; c < 4; ++c) {
                    pal[c] += d0[c] * sa0 + d1[c] * sa1;
                    par[c] += d0[c] * sd0 + d1[c] * sd1;
                }
            }
#pragma unroll
            for (int c = 0; c < 4; ++c) {
                int pk = __builtin_amdgcn_cvt_pk_fp8_f32(d0[c], d1[c], 0, false);
                *(unsigned short*)(h2pre + (size_t)(v0 + c) * KP + f0) = (unsigned short)pk;
            }
        }
    }
#pragma unroll
    for (int off = 32; off; off >>= 1)
#pragma unroll
        for (int c = 0; c < 4; ++c) {
            pal[c] += __shfl_xor(pal[c], off, 64);
            par[c] += __shfl_xor(par[c], off, 64);
        }
    __shared__ float rA[4][4], rB[4][4];
    int wave = tid >> 6, lane = tid & 63;
    if (lane == 0)
#pragma unroll
        for (int c = 0; c < 4; ++c) { rA[wave][c] = pal[c]; rB[wave][c] = par[c]; }
    __syncthreads();
    if (tid < 4) {
        al2[v0 + tid] = rA[0][tid] + rA[1][tid] + rA[2][tid] + rA[3][tid];
        ar2[v0 + tid] = rB[0][tid] + rB[1][tid] + rB[2][tid] + rB[3][tid];
    }
}

// ---------------- layer2 softmax-aggregate: fp8 gather, no max pass, bf16 h2 out ----------------
__global__ __launch_bounds__(256) void k_agg2(
        const unsigned char* __restrict__ h2pre, const float* __restrict__ al, const float* __restrict__ ar,
        const int* __restrict__ rowptr, const int* __restrict__ csrc,
        const bf16_t* __restrict__ bias2, bf16_t* __restrict__ h2) {
    int v = blockIdx.x, tid = threadIdx.x;
    int s0 = rowptr[v], s1 = rowptr[v + 1];
    float arv = ar[v];
    int wave = tid >> 6, lane = tid & 63;

    float acc[8] = {0.f, 0.f, 0.f, 0.f, 0.f, 0.f, 0.f, 0.f};
    float ssum = 0.f;
    __shared__ float sw[256];
    __shared__ int ssrc[256];
    __shared__ float red[4];
    const bool act = tid < (KP / 8);          // 180 lanes cover the 1440-B row
    for (int base = s0; base < s1; base += 256) {
        int e = base + tid;
        float w = 0.f; int si = 0;
        if (e < s1) {
            si = csrc[e];
            float l = al[si] + arv;
            l = l > 0.f ? l : NEG_SLOPE * l;
            w = __expf(l);                    // shift-invariant; |l| small
        }
        ssum += w;
        sw[tid] = w; ssrc[tid] = si;
        __syncthreads();
        int cnt = min(256, s1 - base);
        if (act) {
#pragma unroll 8
            for (int j = 0; j < cnt; ++j) {
                float wj = sw[j];
                const uint2* hp = (const uint2*)(h2pre + (size_t)ssrc[j] * KP);
                uint2 p = hp[tid];
                f32x2 e0 = __builtin_amdgcn_cvt_pk_f32_fp8(p.x, false);
                f32x2 e1 = __builtin_amdgcn_cvt_pk_f32_fp8(p.x, true);
                f32x2 e2 = __builtin_amdgcn_cvt_pk_f32_fp8(p.y, false);
                f32x2 e3 = __builtin_amdgcn_cvt_pk_f32_fp8(p.y, true);
                acc[0] += wj * e0.x; acc[1] += wj * e0.y;
                acc[2] += wj * e1.x; acc[3] += wj * e1.y;
                acc[4] += wj * e2.x; acc[5] += wj * e2.y;
                acc[6] += wj * e3.x; acc[7] += wj * e3.y;
            }
        }
        __syncthreads();
    }
#pragma unroll
    for (int off = 32; off; off >>= 1) ssum += __shfl_xor(ssum, off, 64);
    if (lane == 0) red[wave] = ssum;
    __syncthreads();
    float inv = 1.f / (red[0] + red[1] + red[2] + red[3]);

    if (act) {
        int fb = 8 * tid;
        unsigned short o[8];
#pragma unroll
        for (int t = 0; t < 8; ++t) {
            int f = fb + t;
            o[t] = f2bu((f < FOUT) ? fmaxf(acc[t] * inv + b2f(bias2[f]), 0.f) : 0.f);
        }
        uint4 pk;
        pk.x = (unsigned)o[0] | ((unsigned)o[1] << 16);
        pk.y = (unsigned)o[2] | ((unsigned)o[3] << 16);
        pk.z = (unsigned)o[4] | ((unsigned)o[5] << 16);
        pk.w = (unsigned)o[6] | ((unsigned)o[7] << 16);
        *(uint4*)(h2 + (size_t)v * KP + fb) = pk;
    }
}

// ---------------- final: out = sigmoid(H @ H^T), 128x256 MFMA GEMM ----------------
// Round-10: SINGLE-BARRIER ring.  R9 (128x256, 2 blocks/CU, depth-3 ring) was
// the first structure past the 2-phase ceiling (~310 us).  Its second barrier
// per step ("readers done before re-stage") is provably redundant when the
// stage is issued right after barrier-1 and targets slot (kt+2)%3 == slot
// (kt-1)%3: any wave at step-kt's barrier has completed its step-(kt-1)
// ds_reads (the dependent MFMAs precede the barrier in program order).  DMA
// WAW is also clean: tile kt-1's loads landed before step kt-1 began (its
// vmcnt gate).  So: 45 barriers instead of 90, and staging moves BEFORE the
// compute phase (a full extra phase of DMA latency cover).  Steady state
// 12 loads in flight; wait vmcnt(6) = "oldest 6 (tile kt) landed"; tail
// kt=44 -> vmcnt(0).  Everything else identical to R9 (grouped decode,
// XCD chunking, rect-tri coverage with value-identical mirror writes).
__global__ __launch_bounds__(256, 2) void k_gemm_sig(const bf16_t* __restrict__ Hm,
                                                     float* __restrict__ out) {
    // XCD-bijective chunk swizzle (2256 = 8*282)
    int orig = blockIdx.x;
    int tt = (orig & 7) * (GRID_G / 8) + (orig >> 3);

    // grouped decode: groups of 8 by-rows (last 6), bx-major inside a group
    int u = tt, by0 = 88, R = 6;
#pragma unroll 1
    for (int g = 0; g < 12; ++g) {
        int Rg = (g == 11) ? 6 : 8;
        int sz = (g == 11) ? 12 : (364 - 32 * g);
        if (u < sz) { by0 = 8 * g; R = Rg; break; }
        u -= sz;
    }
    int d = 0;
#pragma unroll 1
    for (;;) {
        int s = 2 * d + 2; if (s > R) s = R;
        if (u < s) break;
        u -= s; ++d;
    }
    const int by = by0 + u;
    const int bx = (by0 >> 1) + d;

    __shared__ __align__(16) char lds[3 * 24576];   // ring: A 8KB + B 16KB per slot

    const int tid  = threadIdx.x;
    const int wave = tid >> 6, lane = tid & 63;
    const int rowA0 = by * 128;          // C rows
    const int colC0 = bx * 256;          // C cols = B rows
    const int r = lane & 15, q4 = lane >> 4;

    // staging source: thread covers 16 B at (row = c*64 + tid>>2, elem col = (tid&3)*8)
    const int srow = tid >> 2, scol = (tid & 3) * 8;
    const bf16_t* gA = Hm + (size_t)(rowA0 + srow) * KP + scol;
    const bf16_t* gB = Hm + (size_t)(colC0 + srow) * KP + scol;

    // fragment read offsets (row stride 64 B within a slot)
    const int aOff = r * 64 + q4 * 16;                       // + mi*1024
    const int bOff = 8192 + (wave * 64 + r) * 64 + q4 * 16;  // + ni*1024

    f32x4 acc[8][4] = {};

// stage K-step kt_ into ring slot sl_: 6 gload_lds per thread (2 A + 4 B)
#define STAGE(sl_, kt_) do {                                                      \
        const int k0_ = (kt_) * 32;                                               \
        char* base_ = lds + (sl_) * 24576;                                        \
        _Pragma("unroll")                                                         \
        for (int c_ = 0; c_ < 2; ++c_)                                            \
            __builtin_amdgcn_global_load_lds(                                     \
                (const __attribute__((address_space(1))) void*)(gA + (size_t)(c_ * 64) * KP + k0_), \
                (__attribute__((address_space(3))) void*)(base_ + c_ * 4096 + wave * 1024 + (lane & 63) * 16), \
                16, 0, 0);                                                        \
        _Pragma("unroll")                                                         \
        for (int c_ = 0; c_ < 4; ++c_)                                            \
            __builtin_amdgcn_global_load_lds(                                     \
                (const __attribute__((address_space(1))) void*)(gB + (size_t)(c_ * 64) * KP + k0_), \
                (__attribute__((address_space(3))) void*)(base_ + 8192 + c_ * 4096 + wave * 1024 + (lane & 63) * 16), \
                16, 0, 0);                                                        \
    } while (0)

    // prologue: stage tiles 0 and 1 (12 loads in flight)
    STAGE(0, 0); STAGE(1, 1);

    int slR = 0, slW = 2;   // read slot, write slot (= slR-1 mod 3)
#pragma unroll 1
    for (int kt = 0; kt < 45; ++kt) {
        // oldest 6 outstanding = tile kt's loads
        if (kt < 44) asm volatile("s_waitcnt vmcnt(6)" ::: "memory");
        else         asm volatile("s_waitcnt vmcnt(0)" ::: "memory");
        __builtin_amdgcn_s_barrier();          // tile kt in LDS; step kt-1 reads done
        __builtin_amdgcn_sched_barrier(0);
        if (kt + 2 < 45) STAGE(slW, kt + 2);   // re-stage the slot freed at kt-1

        const char* S = lds + slR * 24576;
        bf16x8 bfr[4], af[4];
#pragma unroll
        for (int ni = 0; ni < 4; ++ni)
            bfr[ni] = *(const bf16x8*)(S + bOff + ni * 1024);
#pragma unroll
        for (int mi = 0; mi < 4; ++mi)
            af[mi] = *(const bf16x8*)(S + aOff + mi * 1024);
        __builtin_amdgcn_s_setprio(1);
#pragma unroll
        for (int mi = 0; mi < 4; ++mi)
#pragma unroll
            for (int ni = 0; ni < 4; ++ni)
                acc[mi][ni] = __builtin_amdgcn_mfma_f32_16x16x32_bf16(af[mi], bfr[ni], acc[mi][ni], 0, 0, 0);
#pragma unroll
        for (int mi = 0; mi < 4; ++mi)
            af[mi] = *(const bf16x8*)(S + aOff + (mi + 4) * 1024);
#pragma unroll
        for (int mi = 0; mi < 4; ++mi)
#pragma unroll
            for (int ni = 0; ni < 4; ++ni)
                acc[mi + 4][ni] = __builtin_amdgcn_mfma_f32_16x16x32_bf16(af[mi], bfr[ni], acc[mi + 4][ni], 0, 0, 0);
        __builtin_amdgcn_s_setprio(0);
        __builtin_amdgcn_sched_barrier(0);

        slR = (slR == 2) ? 0 : slR + 1;
        slW = (slW == 2) ? 0 : slW + 1;
    }
#undef STAGE

    // epilogue. C/D layout: col=lane&15, row=(lane>>4)*4+reg. NNODES%4==0.
    // Direct store + unconditional mirror store (overlaps write equal values).
#pragma unroll
    for (int mi = 0; mi < 8; ++mi) {
        const int row0 = rowA0 + mi * 16 + q4 * 4;
#pragma unroll
        for (int ni = 0; ni < 4; ++ni) {
            const int col = colC0 + wave * 64 + ni * 16 + r;
            if (col < NNODES && row0 < NNODES) {
                f32x4 s;
#pragma unroll
                for (int r2 = 0; r2 < 4; ++r2)
                    s[r2] = 1.f / (1.f + __expf(-acc[mi][ni][r2]));
#pragma unroll
                for (int r2 = 0; r2 < 4; ++r2)
                    out[(size_t)(row0 + r2) * NNODES + col] = s[r2];
                *(f32x4*)(out + (size_t)col * NNODES + row0) = s;   // mirror
            }
        }
    }
}

extern "C" void kernel_launch(void* const* d_in, const int* in_sizes, int n_in,
                              void* d_out, int out_size, void* d_ws, size_t ws_size,
                              hipStream_t stream) {
    const bf16_t* x   = (const bf16_t*)d_in[0];
    const int*    ei  = (const int*)d_in[1];
    const bf16_t* W1  = (const bf16_t*)d_in[2];
    const bf16_t* as1 = (const bf16_t*)d_in[3];
    const bf16_t* ad1 = (const bf16_t*)d_in[4];
    const bf16_t* b1  = (const bf16_t*)d_in[5];
    const bf16_t* W2  = (const bf16_t*)d_in[6];
    const bf16_t* as2 = (const bf16_t*)d_in[7];
    const bf16_t* ad2 = (const bf16_t*)d_in[8];
    const bf16_t* b2  = (const bf16_t*)d_in[9];
    float* out = (float*)d_out;   // output 0 f32 [N][N], output 1 f32 [2][E]

    // Scratch lives inside d_out's adjacency region (576 MB f32), dead until
    // k_gemm_sig overwrites it. Only h2 (read during final GEMM) is in d_ws.
    char* obuf = (char*)d_out;
    size_t off = 0;
    auto carve = [&](size_t bytes) {
        char* p = obuf + off;
        off += (bytes + 255) & ~(size_t)255;
        return p;
    };
    float* h1pre  = (float*)carve((size_t)NNODES * FHID * 4);
    float* al1    = (float*)carve((size_t)NNODES * 4);
    float* ar1    = (float*)carve((size_t)NNODES * 4);
    float* h1     = (float*)carve((size_t)NNODES * FHID * 4);
    float* al2    = (float*)carve((size_t)NNODES * 4);
    float* ar2    = (float*)carve((size_t)NNODES * 4);
    int*   deg    = (int*)carve((size_t)NNODES * 4);
    int*   rowptr = (int*)carve((size_t)(NNODES + 1) * 4);
    int*   cursor = (int*)carve((size_t)NNODES * 4);
    int*   csrc   = (int*)carve((size_t)NETOT * 4);
    unsigned char* h2pre = (unsigned char*)carve((size_t)NNODES * KP);  // fp8
    bf16_t* h2 = (bf16_t*)d_ws;   // [MP][KP] bf16 = 34.65 MB
    (void)ws_size; (void)in_sizes; (void)n_in; (void)out_size;

    hipLaunchKernelGGL(k_init,    dim3(256), dim3(256), 0, stream, deg, h2);
    hipLaunchKernelGGL(k_count,   dim3((NEDGES + 255) / 256), dim3(256), 0, stream, ei, deg);
    hipLaunchKernelGGL(k_scan,    dim3(1), dim3(1024), 0, stream, deg, rowptr, cursor);
    hipLaunchKernelGGL(k_fill,    dim3((2 * NEDGES + 255) / 256), dim3(256), 0, stream,
                       ei, cursor, csrc, out);
    hipLaunchKernelGGL(k_linear1, dim3((NNODES + 255) / 256), dim3(256), 0, stream,
                       x, W1, as1, ad1, h1pre, al1, ar1);
    hipLaunchKernelGGL(k_agg1,    dim3(NNODES / 4), dim3(256), 0, stream,
                       h1pre, al1, ar1, rowptr, csrc, b1, h1);
    hipLaunchKernelGGL(k_linear2, dim3(NNODES / 4), dim3(256), 0, stream,
                       h1, W2, as2, ad2, h2pre, al2, ar2);
    hipLaunchKernelGGL(k_agg2,    dim3(NNODES), dim3(256), 0, stream,
                       h2pre, al2, ar2, rowptr, csrc, b2, h2);
    hipLaunchKernelGGL(k_gemm_sig, dim3(GRID_G), dim3(256), 0, stream, h2, out);
}